// Round 17
// baseline (2052.750 us; speedup 1.0000x reference)
//
#include <hip/hip_runtime.h>
#include <hip/hip_bf16.h>
#include <stdint.h>

#define T_N 8192
#define K_N 1024
#define D_N 1024
#define LMBDA 5.0f
#define BIGF 3.0e38f
#define CMAX 32
#define THR 26.0f      // 2*lambda + 4 bound + >10 ulp slack (r9-validated)
#define QNAN 0x7FC00000

// ---------------- norms: numpy-pairwise-exact sum of squares per row ----------------
__global__ __launch_bounds__(256) void k_norms(const float* __restrict__ F,
                                               const float* __restrict__ C,
                                               float* __restrict__ sf2,
                                               float* __restrict__ sc2) {
#pragma clang fp contract(off)
  int wave = threadIdx.x >> 6;
  int lane = threadIdx.x & 63;
  int row = blockIdx.x * 4 + wave;
  const float* src;
  float* dst;
  if (row < T_N) { src = F + (size_t)row * D_N; dst = sf2 + row; }
  else           { src = C + (size_t)(row - T_N) * D_N; dst = sc2 + (row - T_N); }
  int leaf = lane >> 3, j = lane & 7;
  const float* p = src + leaf * 128 + j;
  float x = p[0];
  float r = x * x;
#pragma unroll
  for (int i = 1; i < 16; ++i) {
    float y = p[8 * i];
    r = r + y * y;
  }
  r = r + __shfl_xor(r, 1, 64);
  r = r + __shfl_xor(r, 2, 64);
  r = r + __shfl_xor(r, 4, 64);
  r = r + __shfl_xor(r, 8, 64);
  r = r + __shfl_xor(r, 16, 64);
  r = r + __shfl_xor(r, 32, 64);
  if (lane == 0) *dst = r;
}

// ---------------- d2 GEMM: OpenBLAS-faithful f32 64x64 (r4-validated; numerics frozen) -------
__global__ __launch_bounds__(256) void k_gemm(const float* __restrict__ F,
                                              const float* __restrict__ C,
                                              const float* __restrict__ sf2,
                                              const float* __restrict__ sc2,
                                              float* __restrict__ d2) {
  __shared__ float As[32][68];
  __shared__ float Bs[32][68];
  int t0 = (int)(blockIdx.x >> 4) * 64;
  int k0 = (int)(blockIdx.x & 15) * 64;
  int tid = threadIdx.x;
  int tx = tid & 15, ty = tid >> 4;
  float acc[4][4], p0[4][4], p1[4][4];
#pragma unroll
  for (int i = 0; i < 4; ++i)
#pragma unroll
    for (int j = 0; j < 4; ++j) { acc[i][j] = 0.0f; p0[i][j] = 0.0f; p1[i][j] = 0.0f; }
  int r = tid & 63;
  int cbase = (tid >> 6) * 2;
  for (int d0 = 0; d0 < D_N; d0 += 32) {
    __syncthreads();
#pragma unroll
    for (int p = 0; p < 2; ++p) {
      int c4 = cbase + p;
      float4 va = *(const float4*)&F[(size_t)(t0 + r) * D_N + d0 + c4 * 4];
      As[c4 * 4 + 0][r] = va.x; As[c4 * 4 + 1][r] = va.y;
      As[c4 * 4 + 2][r] = va.z; As[c4 * 4 + 3][r] = va.w;
      float4 vb = *(const float4*)&C[(size_t)(k0 + r) * D_N + d0 + c4 * 4];
      Bs[c4 * 4 + 0][r] = vb.x; Bs[c4 * 4 + 1][r] = vb.y;
      Bs[c4 * 4 + 2][r] = vb.z; Bs[c4 * 4 + 3][r] = vb.w;
    }
    __syncthreads();
#pragma unroll
    for (int d = 0; d < 32; ++d) {
      float4 a = *(const float4*)&As[d][ty * 4];
      float4 b = *(const float4*)&Bs[d][tx * 4];
      acc[0][0] = fmaf(a.x, b.x, acc[0][0]); acc[0][1] = fmaf(a.x, b.y, acc[0][1]);
      acc[0][2] = fmaf(a.x, b.z, acc[0][2]); acc[0][3] = fmaf(a.x, b.w, acc[0][3]);
      acc[1][0] = fmaf(a.y, b.x, acc[1][0]); acc[1][1] = fmaf(a.y, b.y, acc[1][1]);
      acc[1][2] = fmaf(a.y, b.z, acc[1][2]); acc[1][3] = fmaf(a.y, b.w, acc[1][3]);
      acc[2][0] = fmaf(a.z, b.x, acc[2][0]); acc[2][1] = fmaf(a.z, b.y, acc[2][1]);
      acc[2][2] = fmaf(a.z, b.z, acc[2][2]); acc[2][3] = fmaf(a.z, b.w, acc[2][3]);
      acc[3][0] = fmaf(a.w, b.x, acc[3][0]); acc[3][1] = fmaf(a.w, b.y, acc[3][1]);
      acc[3][2] = fmaf(a.w, b.z, acc[3][2]); acc[3][3] = fmaf(a.w, b.w, acc[3][3]);
    }
    if (d0 == 352) {
#pragma unroll
      for (int i = 0; i < 4; ++i)
#pragma unroll
        for (int j = 0; j < 4; ++j) { p0[i][j] = acc[i][j]; acc[i][j] = 0.0f; }
    }
    if (d0 == 736) {
#pragma unroll
      for (int i = 0; i < 4; ++i)
#pragma unroll
        for (int j = 0; j < 4; ++j) { p1[i][j] = acc[i][j]; acc[i][j] = 0.0f; }
    }
  }
  {
#pragma clang fp contract(off)
#pragma unroll
    for (int i = 0; i < 4; ++i) {
      int t = t0 + ty * 4 + i;
      float sa = sf2[t];
      float o[4];
#pragma unroll
      for (int j = 0; j < 4; ++j) {
        float dot = (p0[i][j] + p1[i][j]) + acc[i][j];
        float two = 2.0f * dot;
        o[j] = (sa - two) + sc2[k0 + tx * 4 + j];
      }
      float4 ov; ov.x = o[0]; ov.y = o[1]; ov.z = o[2]; ov.w = o[3];
      *(float4*)&d2[(size_t)t * K_N + k0 + tx * 4] = ov;
    }
  }
}

// ---------------- cand: per row, candidate list {k: d <= dmin+THR} + row dmin ----------------
__global__ __launch_bounds__(256) void k_cand(const float* __restrict__ d2,
                                              int2* __restrict__ cand,
                                              float* __restrict__ dminOut) {
  int wave = threadIdx.x >> 6;
  int lane = threadIdx.x & 63;
  int row = blockIdx.x * 4 + wave;
  const float4* p = (const float4*)(d2 + (size_t)row * K_N + lane * 16);
  float4 v0 = p[0], v1 = p[1], v2 = p[2], v3 = p[3];
  float m = fminf(fminf(fminf(v0.x, v0.y), fminf(v0.z, v0.w)),
                  fminf(fminf(v1.x, v1.y), fminf(v1.z, v1.w)));
  float n = fminf(fminf(fminf(v2.x, v2.y), fminf(v2.z, v2.w)),
                  fminf(fminf(v3.x, v3.y), fminf(v3.z, v3.w)));
  m = fminf(m, n);
  m = fminf(m, __shfl_xor(m, 1, 64));
  m = fminf(m, __shfl_xor(m, 2, 64));
  m = fminf(m, __shfl_xor(m, 4, 64));
  m = fminf(m, __shfl_xor(m, 8, 64));
  m = fminf(m, __shfl_xor(m, 16, 64));
  m = fminf(m, __shfl_xor(m, 32, 64));
  if (lane == 0) dminOut[row] = m;
  float thr = m + THR;
  unsigned flags = 0;
#define TESTC(J, VAL) if ((VAL) <= thr) flags |= (1u << (J));
  TESTC(0, v0.x) TESTC(1, v0.y) TESTC(2, v0.z) TESTC(3, v0.w)
  TESTC(4, v1.x) TESTC(5, v1.y) TESTC(6, v1.z) TESTC(7, v1.w)
  TESTC(8, v2.x) TESTC(9, v2.y) TESTC(10, v2.z) TESTC(11, v2.w)
  TESTC(12, v3.x) TESTC(13, v3.y) TESTC(14, v3.z) TESTC(15, v3.w)
#undef TESTC
  int c = __popc(flags);
  int pre = c;
#pragma unroll
  for (int off = 1; off <= 32; off <<= 1) {
    int t = __shfl_up(pre, off, 64);
    if (lane >= off) pre += t;
  }
  int idx = pre - c;
  int2* rowp = cand + (size_t)row * CMAX;
  int kb = lane * 16;
#define EMITC(J, VAL)                                                        \
  if (flags & (1u << (J))) {                                                 \
    if (idx < CMAX) rowp[idx] = make_int2(kb + (J), __float_as_int(VAL));    \
    ++idx;                                                                   \
  }
  EMITC(0, v0.x) EMITC(1, v0.y) EMITC(2, v0.z) EMITC(3, v0.w)
  EMITC(4, v1.x) EMITC(5, v1.y) EMITC(6, v1.z) EMITC(7, v1.w)
  EMITC(8, v2.x) EMITC(9, v2.y) EMITC(10, v2.z) EMITC(11, v2.w)
  EMITC(12, v3.x) EMITC(13, v3.y) EMITC(14, v3.z) EMITC(15, v3.w)
#undef EMITC
}

// ---------------- prev4: per-group (4 rows) slot statics for the G=4 pass1 ----------------
// buf1: lanes<32 = t1-slots (pp, d0lookup, d1own, dinj); lanes>=32 = t0-slots (pp, d0own, d0own, dinj)
// buf2: lanes<32 = t3-slots (pp, d0lookup, d1lookup, dinj); lanes>=32 = t2-slots (same form)
// auxd2[g*32+j] = d2lookup for t3-slot j.  All lookups NaN when k absent (validated NaN-propagation).
__global__ __launch_bounds__(256) void k_prev4(const int2* __restrict__ cand,
                                               int4* __restrict__ buf1,
                                               int4* __restrict__ buf2,
                                               int* __restrict__ auxd2) {
  __shared__ int2 rows[4][5][32];   // [wave][tm1,t0,t1,t2,t3][slot]
  int w = threadIdx.x >> 6, lane = threadIdx.x & 63;
  int g = blockIdx.x * 4 + w;
  int base = 4 * g - 1;
  for (int i = lane; i < 160; i += 64) {
    int rr = i >> 5, ss = i & 31;
    int trow = base + rr;
    rows[w][rr][ss] = (trow >= 0) ? cand[(size_t)trow * CMAX + ss] : make_int2(-2, 0);
  }
  __syncthreads();
  int lo32 = (lane < 32) ? 1 : 0;
  int sl = lane & 31;
  {
    int srcr = lo32 ? 2 : 1;       // t1 : t0
    int2 me = rows[w][srcr][sl];
    int k = me.x;
    int pp = -4, dinj = 0;
#pragma unroll
    for (int i = 0; i < 32; ++i)
      if (rows[w][0][i].x == k) { pp = i * 4; dinj = rows[w][0][i].y; }
    int d0c = QNAN;
#pragma unroll
    for (int i = 0; i < 32; ++i)
      if (rows[w][1][i].x == k) d0c = rows[w][1][i].y;
    if (k < 0) pp = -4;
    int yv = lo32 ? d0c : me.y;
    buf1[(size_t)g * 64 + lane] = make_int4(pp, yv, me.y, dinj);
  }
  {
    int srcr = lo32 ? 4 : 3;       // t3 : t2
    int k = rows[w][srcr][sl].x;
    int pp = -4, dinj = 0;
#pragma unroll
    for (int i = 0; i < 32; ++i)
      if (rows[w][0][i].x == k) { pp = i * 4; dinj = rows[w][0][i].y; }
    int d0c = QNAN, d1c = QNAN, d2c = QNAN;
#pragma unroll
    for (int i = 0; i < 32; ++i) {
      if (rows[w][1][i].x == k) d0c = rows[w][1][i].y;
      if (rows[w][2][i].x == k) d1c = rows[w][2][i].y;
      if (rows[w][3][i].x == k) d2c = rows[w][3][i].y;
    }
    if (k < 0) pp = -4;
    buf2[(size_t)g * 64 + lane] = make_int4(pp, d0c, d1c, dinj);
    if (lo32) auxd2[g * 32 + sl] = d2c;
  }
}

// ---------------- DPP min per 32-lane half (lane 31: lower half; lane 63: upper half) --------
__device__ __forceinline__ float dpp_min32(float x) {
  int t;
  t = __builtin_amdgcn_update_dpp(__float_as_int(x), __float_as_int(x), 0x111, 0xF, 0xF, false);
  x = fminf(x, __int_as_float(t));
  t = __builtin_amdgcn_update_dpp(__float_as_int(x), __float_as_int(x), 0x112, 0xF, 0xF, false);
  x = fminf(x, __int_as_float(t));
  t = __builtin_amdgcn_update_dpp(__float_as_int(x), __float_as_int(x), 0x114, 0xF, 0xF, false);
  x = fminf(x, __int_as_float(t));
  t = __builtin_amdgcn_update_dpp(__float_as_int(x), __float_as_int(x), 0x118, 0xF, 0xF, false);
  x = fminf(x, __int_as_float(t));
  t = __builtin_amdgcn_update_dpp(__float_as_int(x), __float_as_int(x), 0x142, 0xF, 0xF, false); // row_bcast:15
  x = fminf(x, __int_as_float(t));
  return x;
}
__device__ __forceinline__ float rdlane(float x, int l) {
  return __int_as_float(__builtin_amdgcn_readlane(__float_as_int(x), l));
}

// ---------------- pass1: G=4 sparse alpha chain — TWO concurrent bpermutes per FOUR rows ----
// All chains start at the group boundary f_{4g-1} (gathered once, both halves):
//   A: from f_{4g-1}[k] (depth 1..4); B: start t0 from a_in; C: start t1 from a_t0;
//   D: start t2 from a_t1; E: start t3 -> dmin trick + deferred static injection (r16).
//   a_t0 = min(P_pre0, dmin0+a_in); a_t1 = min(P_AB1, dmin1+a_t0)      [red1, in-iter]
//   a_t2 = min(P(min(A2,B2,C2)), dmin2+a_t1); a_t3 = min(P(min(A3,B3,C3,D3)), dmin3+a_t2)
//     [red2, consumed next iteration — pipelined reduce, validated pattern]
//   payload_next = min(A3,B3,C3,D3) per t3-slot; fp = min(gather, dinj + a_t2_prev).
// Every FP op on every surviving path is bit-identical to the reference recurrence.
__global__ __launch_bounds__(64, 1) void k_pass1(const int4* __restrict__ buf1,
                                                 const int4* __restrict__ buf2,
                                                 const int2* __restrict__ cnd,
                                                 const int* __restrict__ auxd2,
                                                 const float* __restrict__ dminArr,
                                                 float* __restrict__ alphaOut) {
  const int lane = threadIdx.x;
  const int lo32 = (lane < 32) ? 1 : 0;
  const int sl = lane & 31;
  const int4* b1p = buf1 + lane;
  const int4* b2p = buf2 + lane;
  const int2* crp = cnd + (size_t)(lo32 ? 3 : 2) * CMAX + sl;   // own-row d (t3|t2)
  const int* axp = auxd2 + sl;
  int4 r1[8], r2[8];
  int2 rc[8];
  int ra[8];
#pragma unroll
  for (int u = 0; u < 8; ++u) {
    r1[u] = b1p[(size_t)u * 64];
    r2[u] = b2p[(size_t)u * 64];
    rc[u] = crp[(size_t)u * 4 * CMAX];
    ra[u] = axp[(size_t)u * 32];
  }
  float pay = 0.0f;           // payload (group 0: all pp=-4, value irrelevant)
  float red2c = BIGF;         // carried red2 (iter 0 -> a_in = 0 exactly)
  float dm2c = 0.0f, dm3c = 0.0f, a1c = 0.0f;
  float areg = 0.0f;
  const int NG = T_N / 4;
  float dmv_next = dminArr[lane];
  for (int gb = 0; gb < NG; gb += 16) {
    float dmv = dmv_next;
    int nb = gb + 16; if (nb >= NG) nb = 0;
    dmv_next = dminArr[nb * 4 + lane];
    for (int g8 = 0; g8 < 16; g8 += 8) {
#pragma unroll
      for (int u = 0; u < 8; ++u) {
        int g = gb + g8 + u;
        int4 pv1 = r1[u];
        int4 pv2 = r2[u];
        int2 cv = rc[u];
        int av = ra[u];
        // both gathers issue immediately (payload from prev iteration)
        int g1 = __builtin_amdgcn_ds_bpermute(pv1.x, __float_as_int(pay));
        int g2 = __builtin_amdgcn_ds_bpermute(pv2.x, __float_as_int(pay));
        // prefetch group g+8
        int gn = g + 8; if (gn > NG - 1) gn = NG - 1;
        r1[u] = b1p[(size_t)gn * 64];
        r2[u] = b2p[(size_t)gn * 64];
        rc[u] = crp[(size_t)gn * 4 * CMAX];
        ra[u] = axp[(size_t)gn * 32];
        // deferred finalize of group g-1 tail (a_{4g-2}, a_{4g-1})
        float Q63 = rdlane(red2c, 63);
        float Q31 = rdlane(red2c, 31);
        float at2p = fminf(Q63, dm2c + a1c);
        float ain = fminf(Q31, dm3c + at2p);
        int posB = 4 * g - 1;
        if (posB >= 0) {
          areg = (((posB - 1) & 63) == lane) ? at2p : areg;
          areg = ((posB & 63) == lane) ? ain : areg;
          if ((posB & 63) == 63) alphaOut[(posB & ~63) + lane] = areg;
        }
        int r0 = 4 * (g8 + u);
        float dm0 = rdlane(dmv, r0);
        float dm1 = rdlane(dmv, r0 + 1);
        float dm2 = rdlane(dmv, r0 + 2);
        float dm3 = rdlane(dmv, r0 + 3);
        // gathered boundary states (deferred E-injection with static dinj)
        float fp1 = (pv1.x < 0) ? BIGF
                                : fminf(__int_as_float(g1), __int_as_float(pv1.w) + at2p);
        float fp2 = (pv2.x < 0) ? BIGF
                                : fminf(__int_as_float(g2), __int_as_float(pv2.w) + at2p);
        // half1: rows t0 (upper lanes: pre0) / t1 (lower lanes: min(A1,B1))
        float d0a = __int_as_float(pv1.y);
        float d1a = __int_as_float(pv1.z);
        float A0a = d0a + (fp1 - LMBDA);
        float A1a = d1a + (A0a - LMBDA);
        float B0a = d0a + ain;
        float B1a = d1a + (B0a - LMBDA);
        float mab1 = fminf(A1a, B1a);
        float x = lo32 ? mab1 : A0a;
        float red1 = dpp_min32(x);
        float at0 = fminf(rdlane(red1, 63), dm0 + ain);
        float at1 = fminf(rdlane(red1, 31), dm1 + at0);
        areg = (((4 * g) & 63) == lane) ? at0 : areg;
        areg = (((4 * g + 1) & 63) == lane) ? at1 : areg;
        // half2: rows t2 (upper: min(A2,B2,C2)) / t3 (lower: min(A3,B3,C3,D3) = payload)
        float d0b = __int_as_float(pv2.y);
        float d1b = __int_as_float(pv2.z);
        float d2s = lo32 ? __int_as_float(av) : __int_as_float(cv.y);
        float dls = __int_as_float(cv.y);
        float A0b = d0b + (fp2 - LMBDA);
        float A1b = d1b + (A0b - LMBDA);
        float A2b = d2s + (A1b - LMBDA);
        float A3b = dls + (A2b - LMBDA);
        float B0b = d0b + ain;
        float B1b = d1b + (B0b - LMBDA);
        float B2b = d2s + (B1b - LMBDA);
        float B3b = dls + (B2b - LMBDA);
        float C1b = d1b + at0;
        float C2b = d2s + (C1b - LMBDA);
        float C3b = dls + (C2b - LMBDA);
        float D2b = d2s + at1;
        float D3b = dls + (D2b - LMBDA);
        float low = fminf(fminf(A3b, B3b), fminf(C3b, D3b));
        float up = fminf(fminf(A2b, B2b), C2b);
        float y = lo32 ? low : up;
        float red2 = dpp_min32(y);
        // carries
        pay = y;              // lanes 0-31 hold the t3-slot payload
        red2c = red2;
        dm2c = dm2; dm3c = dm3; a1c = at1;
      }
    }
  }
  // epilogue: a_{8190}, a_{8191}
  float Q63 = rdlane(red2c, 63);
  float Q31 = rdlane(red2c, 31);
  float at2 = fminf(Q63, dm2c + a1c);
  float at3 = fminf(Q31, dm3c + at2);
  areg = ((8190 & 63) == lane) ? at2 : areg;
  areg = ((8191 & 63) == lane) ? at3 : areg;
  alphaOut[(8191 & ~63) + lane] = areg;
}

// ---------------- pass2: chunked warm-start replay per k (validated r1 == full-history r2) ----------------
#define CH 512
#define WARM 64
__global__ __launch_bounds__(256) void k_pass2(const float* __restrict__ d2,
                                               const float* __restrict__ AOUT,
                                               unsigned* __restrict__ pack) {
  int kb = blockIdx.x & 3;
  int tc = blockIdx.x >> 2;
  int k = kb * 256 + threadIdx.x;
  int ts = tc * CH;
  int start = ts - WARM; if (start < 0) start = 0;
  int end = ts + CH;
  __shared__ float lal[CH + WARM + 1];
  for (int i = threadIdx.x; i < end - start + 1; i += 256) {
    int idx = start - 1 + i;
    lal[i] = (idx < 0) ? 0.0f : AOUT[idx];
  }
  __syncthreads();
  float f = BIGF;
  unsigned s = 0;
#pragma unroll 4
  for (int tau = start; tau < end; ++tau) {
    float a_in = lal[tau - start];
    float d = d2[(size_t)tau * K_N + k];
    float ext = f - LMBDA;
    if (a_in < ext) s = (unsigned)tau;
    f = d + fminf(a_in, ext);
    if (tau >= ts) {
      float a_out = lal[tau - start + 1];
      if (f == a_out) atomicMin(&pack[tau], ((unsigned)k << 13) | s);
    }
  }
}

// ---------------- backtrack: ballot run-skip serial chase + parallel fill (validated r1) ----------------
__global__ __launch_bounds__(256) void k_backtrack(const unsigned* __restrict__ pack,
                                                   unsigned* __restrict__ unitsWs,
                                                   float* __restrict__ outUnits) {
  __shared__ unsigned lp[T_N];
  __shared__ unsigned long long msk[T_N / 64];
  int tid = threadIdx.x;
  for (int i = tid * 4; i < T_N; i += 1024) {
    *(uint4*)&lp[i] = *(const uint4*)&pack[i];
  }
  __syncthreads();
  if (tid < 64) {
    int lane = tid;
    int cur = T_N;
    for (int B = T_N - 64; B >= 0; B -= 64) {
      unsigned long long marks = 0ull;
      if (cur > B) {
        unsigned pk = lp[B + lane];
        int bv = (int)(pk & 8191u);
        unsigned long long run = __ballot(bv == B + lane);
        while (cur > B) {
          int L = cur - 1 - B;
          unsigned long long below = (L == 63) ? ~0ull : ((1ull << (L + 1)) - 1ull);
          unsigned long long nz = (~run) & below;
          if (nz == 0ull) { marks |= below; cur = B; break; }
          int j = 63 - __builtin_clzll(nz);
          marks |= below & ~((1ull << j) - 1ull);
          int nb = __builtin_amdgcn_readlane(bv, j);
          cur = nb;
          if (cur > B + j) cur = B + j;
        }
      }
      if (lane == 0) msk[B >> 6] = marks;
    }
  }
  __syncthreads();
  for (int p = tid; p < T_N; p += 256) {
    int w = p >> 6;
    unsigned long long m = msk[w] & (~0ull << (p & 63));
    while (m == 0ull) { ++w; m = msk[w]; }
    int idx = (w << 6) + (int)__builtin_ctzll(m);
    unsigned g = (lp[idx] >> 13) & 1023u;
    unitsWs[p] = g;
    outUnits[p] = (float)g;
  }
}

// ---------------- gather: quantized[t] = codebook[units[t]] ----------------
__global__ __launch_bounds__(256) void k_gather(const float* __restrict__ C,
                                                const unsigned* __restrict__ unitsWs,
                                                float* __restrict__ out) {
  int t = blockIdx.x;
  unsigned u = unitsWs[t] & 1023u;
  const float4* src = (const float4*)(C + (size_t)u * D_N);
  float4* dst = (float4*)(out + (size_t)t * D_N);
  dst[threadIdx.x] = src[threadIdx.x];
}

extern "C" void kernel_launch(void* const* d_in, const int* in_sizes, int n_in,
                              void* d_out, int out_size, void* d_ws, size_t ws_size,
                              hipStream_t stream) {
  const float* F = (const float*)d_in[0];
  const float* C = (const float*)d_in[1];
  float* out = (float*)d_out;
  float* d2 = out;                                  // reuse quantized region as d2 scratch
  float* outUnits = out + (size_t)T_N * D_N;
  char* ws = (char*)d_ws;
  float* alphaOut = (float*)(ws);                    // 32 KB
  unsigned* pack = (unsigned*)(ws + (32 << 10));     // 32 KB
  unsigned* unitsWs = (unsigned*)(ws + (64 << 10));  // 32 KB
  float* sf2 = (float*)(ws + (96 << 10));            // 32 KB
  float* sc2 = (float*)(ws + (128 << 10));           // 4 KB
  float* dminArr = (float*)(ws + (160 << 10));       // 32 KB
  int2* cand = (int2*)(ws + (1 << 20));              // 2 MB
  int4* buf1 = (int4*)(ws + (3 << 20));              // 2 MB (2048 x 64 x 16B)
  int4* buf2 = (int4*)(ws + (5 << 20));              // 2 MB
  int* auxd2 = (int*)(ws + (7 << 20));               // 256 KB

  k_norms<<<(T_N + K_N) / 4, 256, 0, stream>>>(F, C, sf2, sc2);
  hipMemsetAsync(pack, 0xFF, T_N * sizeof(unsigned), stream);
  hipMemsetAsync(cand, 0xFF, (size_t)T_N * CMAX * sizeof(int2), stream);
  k_gemm<<<(T_N / 64) * (K_N / 64), 256, 0, stream>>>(F, C, sf2, sc2, d2);
  k_cand<<<T_N / 4, 256, 0, stream>>>(d2, cand, dminArr);
  k_prev4<<<(T_N / 4) / 4, 256, 0, stream>>>(cand, buf1, buf2, auxd2);
  k_pass1<<<1, 64, 0, stream>>>(buf1, buf2, cand, auxd2, dminArr, alphaOut);
  k_pass2<<<(T_N / CH) * 4, 256, 0, stream>>>(d2, alphaOut, pack);
  k_backtrack<<<1, 256, 0, stream>>>(pack, unitsWs, outUnits);
  k_gather<<<T_N, 256, 0, stream>>>(C, unitsWs, out);
}

// Round 18
// 1422.751 us; speedup vs baseline: 1.4428x; 1.4428x over previous
//
#include <hip/hip_runtime.h>
#include <hip/hip_bf16.h>
#include <stdint.h>
#include <limits.h>

#define T_N 8192
#define K_N 1024
#define D_N 1024
#define LMBDA 5.0f
#define BIGF 3.0e38f
#define CMAX 32
#define THR 26.0f      // 2*lambda + 4 bound + >10 ulp slack (r9-validated)
#define QNAN 0x7FC00000

// ---------------- norms: numpy-pairwise-exact sum of squares per row ----------------
__global__ __launch_bounds__(256) void k_norms(const float* __restrict__ F,
                                               const float* __restrict__ C,
                                               float* __restrict__ sf2,
                                               float* __restrict__ sc2) {
#pragma clang fp contract(off)
  int wave = threadIdx.x >> 6;
  int lane = threadIdx.x & 63;
  int row = blockIdx.x * 4 + wave;
  const float* src;
  float* dst;
  if (row < T_N) { src = F + (size_t)row * D_N; dst = sf2 + row; }
  else           { src = C + (size_t)(row - T_N) * D_N; dst = sc2 + (row - T_N); }
  int leaf = lane >> 3, j = lane & 7;
  const float* p = src + leaf * 128 + j;
  float x = p[0];
  float r = x * x;
#pragma unroll
  for (int i = 1; i < 16; ++i) {
    float y = p[8 * i];
    r = r + y * y;
  }
  r = r + __shfl_xor(r, 1, 64);
  r = r + __shfl_xor(r, 2, 64);
  r = r + __shfl_xor(r, 4, 64);
  r = r + __shfl_xor(r, 8, 64);
  r = r + __shfl_xor(r, 16, 64);
  r = r + __shfl_xor(r, 32, 64);
  if (lane == 0) *dst = r;
}

// ---------------- d2 GEMM: OpenBLAS-faithful f32 64x64 (r4-validated; numerics frozen) -------
__global__ __launch_bounds__(256) void k_gemm(const float* __restrict__ F,
                                              const float* __restrict__ C,
                                              const float* __restrict__ sf2,
                                              const float* __restrict__ sc2,
                                              float* __restrict__ d2) {
  __shared__ float As[32][68];
  __shared__ float Bs[32][68];
  int t0 = (int)(blockIdx.x >> 4) * 64;
  int k0 = (int)(blockIdx.x & 15) * 64;
  int tid = threadIdx.x;
  int tx = tid & 15, ty = tid >> 4;
  float acc[4][4], p0[4][4], p1[4][4];
#pragma unroll
  for (int i = 0; i < 4; ++i)
#pragma unroll
    for (int j = 0; j < 4; ++j) { acc[i][j] = 0.0f; p0[i][j] = 0.0f; p1[i][j] = 0.0f; }
  int r = tid & 63;
  int cbase = (tid >> 6) * 2;
  for (int d0 = 0; d0 < D_N; d0 += 32) {
    __syncthreads();
#pragma unroll
    for (int p = 0; p < 2; ++p) {
      int c4 = cbase + p;
      float4 va = *(const float4*)&F[(size_t)(t0 + r) * D_N + d0 + c4 * 4];
      As[c4 * 4 + 0][r] = va.x; As[c4 * 4 + 1][r] = va.y;
      As[c4 * 4 + 2][r] = va.z; As[c4 * 4 + 3][r] = va.w;
      float4 vb = *(const float4*)&C[(size_t)(k0 + r) * D_N + d0 + c4 * 4];
      Bs[c4 * 4 + 0][r] = vb.x; Bs[c4 * 4 + 1][r] = vb.y;
      Bs[c4 * 4 + 2][r] = vb.z; Bs[c4 * 4 + 3][r] = vb.w;
    }
    __syncthreads();
#pragma unroll
    for (int d = 0; d < 32; ++d) {
      float4 a = *(const float4*)&As[d][ty * 4];
      float4 b = *(const float4*)&Bs[d][tx * 4];
      acc[0][0] = fmaf(a.x, b.x, acc[0][0]); acc[0][1] = fmaf(a.x, b.y, acc[0][1]);
      acc[0][2] = fmaf(a.x, b.z, acc[0][2]); acc[0][3] = fmaf(a.x, b.w, acc[0][3]);
      acc[1][0] = fmaf(a.y, b.x, acc[1][0]); acc[1][1] = fmaf(a.y, b.y, acc[1][1]);
      acc[1][2] = fmaf(a.y, b.z, acc[1][2]); acc[1][3] = fmaf(a.y, b.w, acc[1][3]);
      acc[2][0] = fmaf(a.z, b.x, acc[2][0]); acc[2][1] = fmaf(a.z, b.y, acc[2][1]);
      acc[2][2] = fmaf(a.z, b.z, acc[2][2]); acc[2][3] = fmaf(a.z, b.w, acc[2][3]);
      acc[3][0] = fmaf(a.w, b.x, acc[3][0]); acc[3][1] = fmaf(a.w, b.y, acc[3][1]);
      acc[3][2] = fmaf(a.w, b.z, acc[3][2]); acc[3][3] = fmaf(a.w, b.w, acc[3][3]);
    }
    if (d0 == 352) {
#pragma unroll
      for (int i = 0; i < 4; ++i)
#pragma unroll
        for (int j = 0; j < 4; ++j) { p0[i][j] = acc[i][j]; acc[i][j] = 0.0f; }
    }
    if (d0 == 736) {
#pragma unroll
      for (int i = 0; i < 4; ++i)
#pragma unroll
        for (int j = 0; j < 4; ++j) { p1[i][j] = acc[i][j]; acc[i][j] = 0.0f; }
    }
  }
  {
#pragma clang fp contract(off)
#pragma unroll
    for (int i = 0; i < 4; ++i) {
      int t = t0 + ty * 4 + i;
      float sa = sf2[t];
      float o[4];
#pragma unroll
      for (int j = 0; j < 4; ++j) {
        float dot = (p0[i][j] + p1[i][j]) + acc[i][j];
        float two = 2.0f * dot;
        o[j] = (sa - two) + sc2[k0 + tx * 4 + j];
      }
      float4 ov; ov.x = o[0]; ov.y = o[1]; ov.z = o[2]; ov.w = o[3];
      *(float4*)&d2[(size_t)t * K_N + k0 + tx * 4] = ov;
    }
  }
}

// ---------------- cand: per row, candidate list {k: d <= dmin+THR} + row dmin ----------------
__global__ __launch_bounds__(256) void k_cand(const float* __restrict__ d2,
                                              int2* __restrict__ cand,
                                              float* __restrict__ dminOut) {
  int wave = threadIdx.x >> 6;
  int lane = threadIdx.x & 63;
  int row = blockIdx.x * 4 + wave;
  const float4* p = (const float4*)(d2 + (size_t)row * K_N + lane * 16);
  float4 v0 = p[0], v1 = p[1], v2 = p[2], v3 = p[3];
  float m = fminf(fminf(fminf(v0.x, v0.y), fminf(v0.z, v0.w)),
                  fminf(fminf(v1.x, v1.y), fminf(v1.z, v1.w)));
  float n = fminf(fminf(fminf(v2.x, v2.y), fminf(v2.z, v2.w)),
                  fminf(fminf(v3.x, v3.y), fminf(v3.z, v3.w)));
  m = fminf(m, n);
  m = fminf(m, __shfl_xor(m, 1, 64));
  m = fminf(m, __shfl_xor(m, 2, 64));
  m = fminf(m, __shfl_xor(m, 4, 64));
  m = fminf(m, __shfl_xor(m, 8, 64));
  m = fminf(m, __shfl_xor(m, 16, 64));
  m = fminf(m, __shfl_xor(m, 32, 64));
  if (lane == 0) dminOut[row] = m;
  float thr = m + THR;
  unsigned flags = 0;
#define TESTC(J, VAL) if ((VAL) <= thr) flags |= (1u << (J));
  TESTC(0, v0.x) TESTC(1, v0.y) TESTC(2, v0.z) TESTC(3, v0.w)
  TESTC(4, v1.x) TESTC(5, v1.y) TESTC(6, v1.z) TESTC(7, v1.w)
  TESTC(8, v2.x) TESTC(9, v2.y) TESTC(10, v2.z) TESTC(11, v2.w)
  TESTC(12, v3.x) TESTC(13, v3.y) TESTC(14, v3.z) TESTC(15, v3.w)
#undef TESTC
  int c = __popc(flags);
  int pre = c;
#pragma unroll
  for (int off = 1; off <= 32; off <<= 1) {
    int t = __shfl_up(pre, off, 64);
    if (lane >= off) pre += t;
  }
  int idx = pre - c;
  int2* rowp = cand + (size_t)row * CMAX;
  int kb = lane * 16;
#define EMITC(J, VAL)                                                        \
  if (flags & (1u << (J))) {                                                 \
    if (idx < CMAX) rowp[idx] = make_int2(kb + (J), __float_as_int(VAL));    \
    ++idx;                                                                   \
  }
  EMITC(0, v0.x) EMITC(1, v0.y) EMITC(2, v0.z) EMITC(3, v0.w)
  EMITC(4, v1.x) EMITC(5, v1.y) EMITC(6, v1.z) EMITC(7, v1.w)
  EMITC(8, v2.x) EMITC(9, v2.y) EMITC(10, v2.z) EMITC(11, v2.w)
  EMITC(12, v3.x) EMITC(13, v3.y) EMITC(14, v3.z) EMITC(15, v3.w)
#undef EMITC
}

// ---------------- slot: per-64-row block, persistent lane-slot assignment ----------------
// Output dslot[t][s]: d_t[k_s] (sign bit set on the chain's FIRST row), QNAN if slot inactive.
// Layout at block start = candidate order of row t0 (blocks independent -> parallel).
// fkOut[b][s] = k held by slot s at block end (for boundary matching).
__global__ __launch_bounds__(64) void k_slot(const int2* __restrict__ cand,
                                             int* __restrict__ dslot,
                                             int* __restrict__ fkOut) {
  __shared__ int posK[1024];
  __shared__ int dtab[32];
  __shared__ int claimed[32];
  __shared__ int fslotL[32];
  __shared__ int2 assignL[64];
  const int lane = threadIdx.x;
  const int b = blockIdx.x;
  const int t0 = b * 64;
  for (int i = lane; i < 1024; i += 64) posK[i] = 0;
  __syncthreads();
  // ---- row t0: slots = candidate order; fresh iff k not in S_{t0-1}
  int2 cv = make_int2(-2, 0);
  if (lane < 32) cv = cand[(size_t)t0 * CMAX + lane];
  int2 cm = make_int2(-2, 0);
  if (lane >= 32 && t0 > 0) {
    cm = cand[(size_t)(t0 - 1) * CMAX + (lane - 32)];
    if (cm.x >= 0) posK[cm.x] = 1;   // membership mark
  }
  __syncthreads();
  int curk = -1, curd = QNAN;
  if (lane < 32 && cv.x >= 0) {
    curk = cv.x;
    bool fresh = (posK[cv.x] == 0);
    curd = fresh ? (cv.y | (int)0x80000000) : cv.y;   // d>0 so sign bit is free
  }
  dslot[(size_t)t0 * 64 + lane] = (curk >= 0) ? curd : QNAN;
  __syncthreads();
  if (lane >= 32 && cm.x >= 0) posK[cm.x] = 0;    // clear S_{t0-1}
  __syncthreads();
  int prevk = (lane < 32) ? cv.x : -2;
  if (lane < 32 && cv.x >= 0) posK[cv.x] = lane + 1;  // publish S_{t0}
  __syncthreads();
  // ---- rows t0+1 .. t0+63
  for (int rr = 1; rr < 64; ++rr) {
    int t = t0 + rr;
    int2 c2 = make_int2(-2, 0);
    if (lane < 32) {
      c2 = cand[(size_t)t * CMAX + lane];
      claimed[lane] = 0;
    }
    assignL[lane] = make_int2(INT_MIN, 0);
    __syncthreads();
    if (lane < 32 && prevk >= 0) posK[prevk] = 0;   // clear S_{t-1}
    __syncthreads();
    if (lane < 32 && c2.x >= 0) { posK[c2.x] = lane + 1; dtab[lane] = c2.y; }  // publish S_t
    __syncthreads();
    // continuation / death
    int j1 = (curk >= 0) ? posK[curk] : 0;
    if (curk >= 0 && j1 > 0) {
      claimed[j1 - 1] = 1;
    } else if (curk >= 0) {
      curk = -1; curd = QNAN;
    }
    __syncthreads();
    if (curk >= 0 && j1 > 0) curd = dtab[j1 - 1];   // plain (no fresh bit)
    // allocation of new chains
    bool isNew = (lane < 32) && (c2.x >= 0) && (claimed[lane] == 0);
    unsigned long long newb = __ballot(isNew);
    unsigned long long freeb = __ballot(curk < 0);
    int frank = __popcll(freeb & ((1ull << lane) - 1ull));
    if (curk < 0 && frank < 32) fslotL[frank] = lane;
    __syncthreads();
    if (isNew) {
      int nrank = __popcll(newb & ((1ull << lane) - 1ull));
      int s = fslotL[nrank];
      assignL[s] = make_int2(c2.x, c2.y | (int)0x80000000);
    }
    __syncthreads();
    int2 as = assignL[lane];
    if (as.x != INT_MIN) { curk = as.x; curd = as.y; }
    dslot[(size_t)t * 64 + lane] = (curk >= 0) ? curd : QNAN;
    prevk = (lane < 32) ? c2.x : -2;
    __syncthreads();
  }
  fkOut[b * 64 + lane] = curk;
}

// ---------------- bmap: boundary slot map — new slot s' -> old slot byteaddr of same k ------
__global__ __launch_bounds__(64) void k_bmap(const int2* __restrict__ cand,
                                             const int* __restrict__ fk,
                                             int* __restrict__ bmap) {
  __shared__ int fkL[64];
  int b = blockIdx.x, lane = threadIdx.x;
  int out = -4;
  if (b > 0) {
    fkL[lane] = fk[(b - 1) * 64 + lane];
    __syncthreads();
    if (lane < 32) {
      int k = cand[(size_t)(b * 64) * CMAX + lane].x;
      if (k >= 0) {
#pragma unroll
        for (int i = 0; i < 64; ++i)
          if (fkL[i] == k) out = i * 4;
      }
    }
  }
  bmap[b * 64 + lane] = out;
}

// ---------------- DPP full-wave min (result valid in lane 63; r5-validated chain) ------------
__device__ __forceinline__ float dpp_min64(float x) {
  int t;
  t = __builtin_amdgcn_update_dpp(__float_as_int(x), __float_as_int(x), 0x111, 0xF, 0xF, false);
  x = fminf(x, __int_as_float(t));
  t = __builtin_amdgcn_update_dpp(__float_as_int(x), __float_as_int(x), 0x112, 0xF, 0xF, false);
  x = fminf(x, __int_as_float(t));
  t = __builtin_amdgcn_update_dpp(__float_as_int(x), __float_as_int(x), 0x114, 0xF, 0xF, false);
  x = fminf(x, __int_as_float(t));
  t = __builtin_amdgcn_update_dpp(__float_as_int(x), __float_as_int(x), 0x118, 0xF, 0xF, false);
  x = fminf(x, __int_as_float(t));
  t = __builtin_amdgcn_update_dpp(__float_as_int(x), __float_as_int(x), 0x142, 0xF, 0xF, false); // row_bcast:15
  x = fminf(x, __int_as_float(t));
  t = __builtin_amdgcn_update_dpp(__float_as_int(x), __float_as_int(x), 0x143, 0xF, 0xF, false); // row_bcast:31
  x = fminf(x, __int_as_float(t));
  return x;
}
__device__ __forceinline__ float rdlane(float x, int l) {
  return __int_as_float(__builtin_amdgcn_readlane(__float_as_int(x), l));
}

// ---------------- pass1: slot-resident chains — NO per-row gather ----------------
// Per row (r6/r16-validated identities, bit-exact):
//   f_{t-1} = min(pre_{t-1}, d_{t-1} + a_{t-2})
//   a_{t-1} = min(P_{t-1}, dmin_{t-1} + a_{t-2})   [P = pipelined reduce, 1-row slack]
//   pre_t   = d_t + (fp - L),  fp = fresh ? BIG : f_{t-1}   (fresh = sign bit of dslot)
// One bpermute per 64-row block remaps f to the next block's slot layout.
__global__ __launch_bounds__(64, 1) void k_pass1(const int* __restrict__ dslot,
                                                 const int* __restrict__ bmap,
                                                 const float* __restrict__ dminArr,
                                                 float* __restrict__ alphaOut) {
  const int lane = threadIdx.x;
  int rgd[8];
#pragma unroll
  for (int u = 0; u < 8; ++u) rgd[u] = dslot[u * 64 + lane];
  float f = BIGF;
  float alpha = 0.0f;       // entering iter t: a_{t-2}
  float redc = BIGF;        // pending reduce (init -> a_{-1} = min(BIG, 0+0) = 0)
  float dmp = 0.0f;         // dmin_{t-1}
  float prev_pre = BIGF;
  float dprev = BIGF;
  float areg = 0.0f;
  float dmv = dminArr[lane];
  float dmv_next;
  int bmv = bmap[lane];     // block 0: all -4
  int bmv_next;
  for (int base = 0; base < T_N; base += 64) {
    int nb = base + 64; if (nb >= T_N) nb = 0;
    dmv_next = dminArr[nb + lane];
    int bN = (base >> 6) + 1; if (bN > (T_N / 64) - 1) bN = 0;
    bmv_next = bmap[bN * 64 + lane];
    for (int b8 = 0; b8 < 64; b8 += 8) {
#pragma unroll
      for (int u = 0; u < 8; ++u) {
        int t = base + b8 + u;
        int db = rgd[u];
        int pt = t + 8; if (pt > T_N - 1) pt = T_N - 1;
        rgd[u] = dslot[pt * 64 + lane];
        // f_{t-1} (old layout), then remap at block boundary
        f = fminf(prev_pre, dprev + alpha);
        if (u == 0) {
          if (b8 == 0) {
            int g = __builtin_amdgcn_ds_bpermute(bmv, __float_as_int(f));
            f = (bmv < 0) ? BIGF : __int_as_float(g);
          }
        }
        // finalize a_{t-1}
        float P = rdlane(redc, 63);
        alpha = fminf(P, dmp + alpha);
        int pos = t - 1;
        if (pos >= 0) {
          areg = ((pos & 63) == lane) ? alpha : areg;
          if ((pos & 63) == 63) alphaOut[(pos & ~63) + lane] = areg;
        }
        // pre_t + pipelined reduce
        bool fresh = (db < 0);
        float d = __int_as_float(db & 0x7fffffff);
        float fp = fresh ? BIGF : f;
        float pre = d + (fp - LMBDA);
        redc = dpp_min64(pre);
        dmp = rdlane(dmv, t & 63);
        dprev = d;
        prev_pre = pre;
      }
    }
    dmv = dmv_next;
    bmv = bmv_next;
  }
  // epilogue: a_{T-1}
  float P = rdlane(redc, 63);
  alpha = fminf(P, dmp + alpha);
  areg = (lane == 63) ? alpha : areg;
  alphaOut[T_N - 64 + lane] = areg;
}

// ---------------- pass2: chunked warm-start replay per k (validated r1 == full-history r2) ----------------
#define CH 512
#define WARM 64
__global__ __launch_bounds__(256) void k_pass2(const float* __restrict__ d2,
                                               const float* __restrict__ AOUT,
                                               unsigned* __restrict__ pack) {
  int kb = blockIdx.x & 3;
  int tc = blockIdx.x >> 2;
  int k = kb * 256 + threadIdx.x;
  int ts = tc * CH;
  int start = ts - WARM; if (start < 0) start = 0;
  int end = ts + CH;
  __shared__ float lal[CH + WARM + 1];
  for (int i = threadIdx.x; i < end - start + 1; i += 256) {
    int idx = start - 1 + i;
    lal[i] = (idx < 0) ? 0.0f : AOUT[idx];
  }
  __syncthreads();
  float f = BIGF;
  unsigned s = 0;
#pragma unroll 4
  for (int tau = start; tau < end; ++tau) {
    float a_in = lal[tau - start];
    float d = d2[(size_t)tau * K_N + k];
    float ext = f - LMBDA;
    if (a_in < ext) s = (unsigned)tau;
    f = d + fminf(a_in, ext);
    if (tau >= ts) {
      float a_out = lal[tau - start + 1];
      if (f == a_out) atomicMin(&pack[tau], ((unsigned)k << 13) | s);
    }
  }
}

// ---------------- backtrack: ballot run-skip serial chase + parallel fill (validated r1) ----------------
__global__ __launch_bounds__(256) void k_backtrack(const unsigned* __restrict__ pack,
                                                   unsigned* __restrict__ unitsWs,
                                                   float* __restrict__ outUnits) {
  __shared__ unsigned lp[T_N];
  __shared__ unsigned long long msk[T_N / 64];
  int tid = threadIdx.x;
  for (int i = tid * 4; i < T_N; i += 1024) {
    *(uint4*)&lp[i] = *(const uint4*)&pack[i];
  }
  __syncthreads();
  if (tid < 64) {
    int lane = tid;
    int cur = T_N;
    for (int B = T_N - 64; B >= 0; B -= 64) {
      unsigned long long marks = 0ull;
      if (cur > B) {
        unsigned pk = lp[B + lane];
        int bv = (int)(pk & 8191u);
        unsigned long long run = __ballot(bv == B + lane);
        while (cur > B) {
          int L = cur - 1 - B;
          unsigned long long below = (L == 63) ? ~0ull : ((1ull << (L + 1)) - 1ull);
          unsigned long long nz = (~run) & below;
          if (nz == 0ull) { marks |= below; cur = B; break; }
          int j = 63 - __builtin_clzll(nz);
          marks |= below & ~((1ull << j) - 1ull);
          int nb = __builtin_amdgcn_readlane(bv, j);
          cur = nb;
          if (cur > B + j) cur = B + j;
        }
      }
      if (lane == 0) msk[B >> 6] = marks;
    }
  }
  __syncthreads();
  for (int p = tid; p < T_N; p += 256) {
    int w = p >> 6;
    unsigned long long m = msk[w] & (~0ull << (p & 63));
    while (m == 0ull) { ++w; m = msk[w]; }
    int idx = (w << 6) + (int)__builtin_ctzll(m);
    unsigned g = (lp[idx] >> 13) & 1023u;
    unitsWs[p] = g;
    outUnits[p] = (float)g;
  }
}

// ---------------- gather: quantized[t] = codebook[units[t]] ----------------
__global__ __launch_bounds__(256) void k_gather(const float* __restrict__ C,
                                                const unsigned* __restrict__ unitsWs,
                                                float* __restrict__ out) {
  int t = blockIdx.x;
  unsigned u = unitsWs[t] & 1023u;
  const float4* src = (const float4*)(C + (size_t)u * D_N);
  float4* dst = (float4*)(out + (size_t)t * D_N);
  dst[threadIdx.x] = src[threadIdx.x];
}

extern "C" void kernel_launch(void* const* d_in, const int* in_sizes, int n_in,
                              void* d_out, int out_size, void* d_ws, size_t ws_size,
                              hipStream_t stream) {
  const float* F = (const float*)d_in[0];
  const float* C = (const float*)d_in[1];
  float* out = (float*)d_out;
  float* d2 = out;                                  // reuse quantized region as d2 scratch
  float* outUnits = out + (size_t)T_N * D_N;
  char* ws = (char*)d_ws;
  float* alphaOut = (float*)(ws);                    // 32 KB
  unsigned* pack = (unsigned*)(ws + (32 << 10));     // 32 KB
  unsigned* unitsWs = (unsigned*)(ws + (64 << 10));  // 32 KB
  float* sf2 = (float*)(ws + (96 << 10));            // 32 KB
  float* sc2 = (float*)(ws + (128 << 10));           // 4 KB
  float* dminArr = (float*)(ws + (160 << 10));       // 32 KB
  int2* cand = (int2*)(ws + (1 << 20));              // 2 MB
  int* dslot = (int*)(ws + (3 << 20));               // 2 MB (8192 x 64 x 4B)
  int* fk = (int*)(ws + (5 << 20));                  // 32 KB
  int* bmap = (int*)(ws + (5 << 20) + (64 << 10));   // 32 KB

  k_norms<<<(T_N + K_N) / 4, 256, 0, stream>>>(F, C, sf2, sc2);
  hipMemsetAsync(pack, 0xFF, T_N * sizeof(unsigned), stream);
  hipMemsetAsync(cand, 0xFF, (size_t)T_N * CMAX * sizeof(int2), stream);
  k_gemm<<<(T_N / 64) * (K_N / 64), 256, 0, stream>>>(F, C, sf2, sc2, d2);
  k_cand<<<T_N / 4, 256, 0, stream>>>(d2, cand, dminArr);
  k_slot<<<T_N / 64, 64, 0, stream>>>(cand, dslot, fk);
  k_bmap<<<T_N / 64, 64, 0, stream>>>(cand, fk, bmap);
  k_pass1<<<1, 64, 0, stream>>>(dslot, bmap, dminArr, alphaOut);
  k_pass2<<<(T_N / CH) * 4, 256, 0, stream>>>(d2, alphaOut, pack);
  k_backtrack<<<1, 256, 0, stream>>>(pack, unitsWs, outUnits);
  k_gather<<<T_N, 256, 0, stream>>>(C, unitsWs, out);
}

// Round 19
// 951.515 us; speedup vs baseline: 2.1573x; 1.4952x over previous
//
#include <hip/hip_runtime.h>
#include <hip/hip_bf16.h>
#include <stdint.h>

#define T_N 8192
#define K_N 1024
#define D_N 1024
#define LMBDA 5.0f
#define BIGF 3.0e38f
#define CMAX 32
#define THR 26.0f      // 2*lambda + 4 bound + >10 ulp slack (r9-validated)
#define QNAN 0x7FC00000

// ---------------- norms: numpy-pairwise-exact sum of squares per row ----------------
__global__ __launch_bounds__(256) void k_norms(const float* __restrict__ F,
                                               const float* __restrict__ C,
                                               float* __restrict__ sf2,
                                               float* __restrict__ sc2) {
#pragma clang fp contract(off)
  int wave = threadIdx.x >> 6;
  int lane = threadIdx.x & 63;
  int row = blockIdx.x * 4 + wave;
  const float* src;
  float* dst;
  if (row < T_N) { src = F + (size_t)row * D_N; dst = sf2 + row; }
  else           { src = C + (size_t)(row - T_N) * D_N; dst = sc2 + (row - T_N); }
  int leaf = lane >> 3, j = lane & 7;
  const float* p = src + leaf * 128 + j;
  float x = p[0];
  float r = x * x;
#pragma unroll
  for (int i = 1; i < 16; ++i) {
    float y = p[8 * i];
    r = r + y * y;
  }
  r = r + __shfl_xor(r, 1, 64);
  r = r + __shfl_xor(r, 2, 64);
  r = r + __shfl_xor(r, 4, 64);
  r = r + __shfl_xor(r, 8, 64);
  r = r + __shfl_xor(r, 16, 64);
  r = r + __shfl_xor(r, 32, 64);
  if (lane == 0) *dst = r;
}

// ---------------- d2 GEMM: OpenBLAS-faithful f32, 64x128 tile / 4x8 microtile ----------------
// Per-output numerics IDENTICAL to r4-validated: strictly d-ascending fmaf chain,
// snapshots after d=383 (dot=p0) and d=767 (dot=p0+p1); final dsum=(p0+p1)+p2.
__global__ __launch_bounds__(256) void k_gemm(const float* __restrict__ F,
                                              const float* __restrict__ C,
                                              const float* __restrict__ sf2,
                                              const float* __restrict__ sc2,
                                              float* __restrict__ d2) {
  __shared__ float As[32][68];    // [d][t]
  __shared__ float Bs[32][132];   // [d][k]
  int t0 = (int)(blockIdx.x >> 3) * 64;
  int k0 = (int)(blockIdx.x & 7) * 128;
  int tid = threadIdx.x;
  int tx = tid & 15, ty = tid >> 4;     // k: tx*8, t: ty*4
  float dot[4][8], acc[4][8];
#pragma unroll
  for (int i = 0; i < 4; ++i)
#pragma unroll
    for (int j = 0; j < 8; ++j) { dot[i][j] = 0.0f; acc[i][j] = 0.0f; }
  int ra = tid & 63, ca = (tid >> 6) * 8;     // A: row ra, d-cols ca..ca+7
  int rb = tid & 127, cb = (tid >> 7) * 16;   // B: row rb, d-cols cb..cb+15
  for (int d0 = 0; d0 < D_N; d0 += 32) {
    __syncthreads();
    {
      const float* fa = &F[(size_t)(t0 + ra) * D_N + d0 + ca];
      float4 a0 = *(const float4*)fa;
      float4 a1 = *(const float4*)(fa + 4);
      As[ca + 0][ra] = a0.x; As[ca + 1][ra] = a0.y; As[ca + 2][ra] = a0.z; As[ca + 3][ra] = a0.w;
      As[ca + 4][ra] = a1.x; As[ca + 5][ra] = a1.y; As[ca + 6][ra] = a1.z; As[ca + 7][ra] = a1.w;
      const float* fb = &C[(size_t)(k0 + rb) * D_N + d0 + cb];
      float4 b0 = *(const float4*)fb;
      float4 b1 = *(const float4*)(fb + 4);
      float4 b2 = *(const float4*)(fb + 8);
      float4 b3 = *(const float4*)(fb + 12);
      Bs[cb + 0][rb] = b0.x; Bs[cb + 1][rb] = b0.y; Bs[cb + 2][rb] = b0.z; Bs[cb + 3][rb] = b0.w;
      Bs[cb + 4][rb] = b1.x; Bs[cb + 5][rb] = b1.y; Bs[cb + 6][rb] = b1.z; Bs[cb + 7][rb] = b1.w;
      Bs[cb + 8][rb] = b2.x; Bs[cb + 9][rb] = b2.y; Bs[cb + 10][rb] = b2.z; Bs[cb + 11][rb] = b2.w;
      Bs[cb + 12][rb] = b3.x; Bs[cb + 13][rb] = b3.y; Bs[cb + 14][rb] = b3.z; Bs[cb + 15][rb] = b3.w;
    }
    __syncthreads();
#pragma unroll
    for (int d = 0; d < 32; ++d) {
      float4 a = *(const float4*)&As[d][ty * 4];
      float4 b0 = *(const float4*)&Bs[d][tx * 8];
      float4 b1 = *(const float4*)&Bs[d][tx * 8 + 4];
      float av[4] = {a.x, a.y, a.z, a.w};
      float bv[8] = {b0.x, b0.y, b0.z, b0.w, b1.x, b1.y, b1.z, b1.w};
#pragma unroll
      for (int i = 0; i < 4; ++i)
#pragma unroll
        for (int j = 0; j < 8; ++j)
          acc[i][j] = fmaf(av[i], bv[j], acc[i][j]);
    }
    if (d0 == 352) {      // end of panel [0,384): dot = p0, restart chain
#pragma unroll
      for (int i = 0; i < 4; ++i)
#pragma unroll
        for (int j = 0; j < 8; ++j) { dot[i][j] = acc[i][j]; acc[i][j] = 0.0f; }
    }
    if (d0 == 736) {      // end of panel [384,768): dot = p0 + p1 (rounded add)
#pragma unroll
      for (int i = 0; i < 4; ++i)
#pragma unroll
        for (int j = 0; j < 8; ++j) { dot[i][j] = dot[i][j] + acc[i][j]; acc[i][j] = 0.0f; }
    }
  }
  {
#pragma clang fp contract(off)
#pragma unroll
    for (int i = 0; i < 4; ++i) {
      int t = t0 + ty * 4 + i;
      float sa = sf2[t];
      float o[8];
#pragma unroll
      for (int j = 0; j < 8; ++j) {
        float dsum = dot[i][j] + acc[i][j];      // ((p0+p1)+p2), rounded adds
        float two = 2.0f * dsum;                 // exact
        o[j] = (sa - two) + sc2[k0 + tx * 8 + j];
      }
      float4 o0; o0.x = o[0]; o0.y = o[1]; o0.z = o[2]; o0.w = o[3];
      float4 o1; o1.x = o[4]; o1.y = o[5]; o1.z = o[6]; o1.w = o[7];
      float* dp = &d2[(size_t)t * K_N + k0 + tx * 8];
      *(float4*)dp = o0;
      *(float4*)(dp + 4) = o1;
    }
  }
}

// ---------------- cand: per row, candidate list {k: d <= dmin+THR} + row dmin ----------------
__global__ __launch_bounds__(256) void k_cand(const float* __restrict__ d2,
                                              int2* __restrict__ cand,
                                              float* __restrict__ dminOut) {
  int wave = threadIdx.x >> 6;
  int lane = threadIdx.x & 63;
  int row = blockIdx.x * 4 + wave;
  const float4* p = (const float4*)(d2 + (size_t)row * K_N + lane * 16);
  float4 v0 = p[0], v1 = p[1], v2 = p[2], v3 = p[3];
  float m = fminf(fminf(fminf(v0.x, v0.y), fminf(v0.z, v0.w)),
                  fminf(fminf(v1.x, v1.y), fminf(v1.z, v1.w)));
  float n = fminf(fminf(fminf(v2.x, v2.y), fminf(v2.z, v2.w)),
                  fminf(fminf(v3.x, v3.y), fminf(v3.z, v3.w)));
  m = fminf(m, n);
  m = fminf(m, __shfl_xor(m, 1, 64));
  m = fminf(m, __shfl_xor(m, 2, 64));
  m = fminf(m, __shfl_xor(m, 4, 64));
  m = fminf(m, __shfl_xor(m, 8, 64));
  m = fminf(m, __shfl_xor(m, 16, 64));
  m = fminf(m, __shfl_xor(m, 32, 64));
  if (lane == 0) dminOut[row] = m;
  float thr = m + THR;
  unsigned flags = 0;
#define TESTC(J, VAL) if ((VAL) <= thr) flags |= (1u << (J));
  TESTC(0, v0.x) TESTC(1, v0.y) TESTC(2, v0.z) TESTC(3, v0.w)
  TESTC(4, v1.x) TESTC(5, v1.y) TESTC(6, v1.z) TESTC(7, v1.w)
  TESTC(8, v2.x) TESTC(9, v2.y) TESTC(10, v2.z) TESTC(11, v2.w)
  TESTC(12, v3.x) TESTC(13, v3.y) TESTC(14, v3.z) TESTC(15, v3.w)
#undef TESTC
  int c = __popc(flags);
  int pre = c;
#pragma unroll
  for (int off = 1; off <= 32; off <<= 1) {
    int t = __shfl_up(pre, off, 64);
    if (lane >= off) pre += t;
  }
  int idx = pre - c;
  int2* rowp = cand + (size_t)row * CMAX;
  int kb = lane * 16;
#define EMITC(J, VAL)                                                        \
  if (flags & (1u << (J))) {                                                 \
    if (idx < CMAX) rowp[idx] = make_int2(kb + (J), __float_as_int(VAL));    \
    ++idx;                                                                   \
  }
  EMITC(0, v0.x) EMITC(1, v0.y) EMITC(2, v0.z) EMITC(3, v0.w)
  EMITC(4, v1.x) EMITC(5, v1.y) EMITC(6, v1.z) EMITC(7, v1.w)
  EMITC(8, v2.x) EMITC(9, v2.y) EMITC(10, v2.z) EMITC(11, v2.w)
  EMITC(12, v3.x) EMITC(13, v3.y) EMITC(14, v3.z) EMITC(15, v3.w)
#undef EMITC
}

// ---------------- prev2: per-pair lane data (pp, d0, d1s) for the G=2 pass1 ----------------
__global__ __launch_bounds__(256) void k_prev2(const int2* __restrict__ cand,
                                               int4* __restrict__ pairbuf) {
  __shared__ int km1k[4][32];
  __shared__ int km1d[4][32];
  __shared__ int kt0k[4][32];
  __shared__ int kt0d[4][32];
  int w = threadIdx.x >> 6, lane = threadIdx.x & 63;
  int p = blockIdx.x * 4 + w;
  int t0 = 2 * p, t1 = 2 * p + 1, tm1 = t0 - 1;
  if (lane < 32) {
    int2 c0 = cand[(size_t)t0 * CMAX + lane];
    kt0k[w][lane] = c0.x; kt0d[w][lane] = c0.y;
  } else {
    int j = lane - 32;
    int2 cm = (p > 0) ? cand[(size_t)tm1 * CMAX + j] : make_int2(-2, 0);
    km1k[w][j] = cm.x; km1d[w][j] = cm.y;
  }
  __syncthreads();
  int4 out;
  if (lane < 32) {
    int2 c1 = cand[(size_t)t1 * CMAX + lane];
    int k1 = c1.x;
    int pp2 = -4, d0 = QNAN, d1s = 0;
    bool in0 = false;
#pragma unroll
    for (int i = 0; i < 32; ++i) if (kt0k[w][i] == k1) { d0 = kt0d[w][i]; in0 = true; }
#pragma unroll
    for (int i = 0; i < 32; ++i) if (km1k[w][i] == k1) { pp2 = i * 4; d1s = km1d[w][i]; }
    if (!in0 || k1 < 0) { pp2 = -4; d0 = QNAN; }
    out = make_int4(pp2, d0, d1s, 0);
  } else {
    int i0 = lane - 32;
    int k0 = kt0k[w][i0];
    int d0 = kt0d[w][i0];
    int pp = -4, d1s = 0;
#pragma unroll
    for (int i = 0; i < 32; ++i) if (km1k[w][i] == k0) { pp = i * 4; d1s = km1d[w][i]; }
    if (k0 < 0) pp = -4;   // sentinel slot (d0 already NaN)
    out = make_int4(pp, d0, d1s, 0);
  }
  pairbuf[(size_t)p * 64 + lane] = out;
}

// ---------------- DPP min per 32-lane half (lane 31: lower half; lane 63: upper half) --------
__device__ __forceinline__ float dpp_min32(float x) {
  int t;
  t = __builtin_amdgcn_update_dpp(__float_as_int(x), __float_as_int(x), 0x111, 0xF, 0xF, false);
  x = fminf(x, __int_as_float(t));
  t = __builtin_amdgcn_update_dpp(__float_as_int(x), __float_as_int(x), 0x112, 0xF, 0xF, false);
  x = fminf(x, __int_as_float(t));
  t = __builtin_amdgcn_update_dpp(__float_as_int(x), __float_as_int(x), 0x114, 0xF, 0xF, false);
  x = fminf(x, __int_as_float(t));
  t = __builtin_amdgcn_update_dpp(__float_as_int(x), __float_as_int(x), 0x118, 0xF, 0xF, false);
  x = fminf(x, __int_as_float(t));
  t = __builtin_amdgcn_update_dpp(__float_as_int(x), __float_as_int(x), 0x142, 0xF, 0xF, false); // row_bcast:15
  x = fminf(x, __int_as_float(t));
  return x;
}
__device__ __forceinline__ float rdlane(float x, int l) {
  return __int_as_float(__builtin_amdgcn_readlane(__float_as_int(x), l));
}

// ---------------- pass1: G=2 sparse chain — bpermute payload is alpha-free mab (r16, 559us) --
__global__ __launch_bounds__(64, 1) void k_pass1(const int4* __restrict__ pairbuf,
                                                 const int2* __restrict__ cand,
                                                 const float* __restrict__ dminArr,
                                                 float* __restrict__ alphaOut) {
  const int lane = threadIdx.x;
  const int4* basep = pairbuf + lane;
  const int2* basec = cand + (lane & 31);
  int4 rg[8];
  int2 rgc[8];
#pragma unroll
  for (int u = 0; u < 8; ++u) {
    rg[u] = basep[(size_t)u * 64];
    rgc[u] = basec[(size_t)(2 * u + 1) * CMAX];
  }
  float mabprev = BIGF;     // mab of previous pair (lanes 0-31 meaningful)
  float alpha = 0.0f;       // entering iter p: a_{2p-2}
  float redAB = 0.0f;       // pending lane-31 reduce (P_AB1 of previous pair)
  float dmT1prev = 0.0f;    // dmin_{2p-1}
  float areg = 0.0f;
  float dmv_next = dminArr[lane];
  const int NP = T_N / 2;
  for (int pb32 = 0; pb32 < NP; pb32 += 32) {
    float dmv = dmv_next;
    int nb = pb32 + 32; if (nb >= NP) nb = 0;
    dmv_next = dminArr[2 * nb + lane];
    for (int pb8 = 0; pb8 < 32; pb8 += 8) {
#pragma unroll
      for (int u = 0; u < 8; ++u) {
        int p = pb32 + pb8 + u;
        int4 pv = rg[u];
        int2 cv = rgc[u];
        float aEnter = alpha;                        // a_{2p-2}
        // the pair's single bpermute: payload mab (alpha-free, ready since last iter)
        int g1 = __builtin_amdgcn_ds_bpermute(pv.x, __float_as_int(mabprev));
        // prefetch pair p+8
        int pn = p + 8; if (pn > NP - 1) pn = NP - 1;
        rg[u] = basep[(size_t)pn * 64];
        rgc[u] = basec[(size_t)(2 * pn + 1) * CMAX];
        // finalize a_{2p-1} (off the gather chain)
        float Pab = rdlane(redAB, 31);
        alpha = fminf(Pab, dmT1prev + aEnter);       // a_{2p-1}
        int posA = 2 * p - 1;
        if (posA >= 0) {
          areg = ((posA & 63) == lane) ? alpha : areg;
          if ((posA & 63) == 63) alphaOut[(posA & ~63) + lane] = areg;
        }
        int r0 = 2 * (pb8 + u);
        float dm0 = rdlane(dmv, r0);
        float dm1 = rdlane(dmv, r0 + 1);
        // fp = min(mab_g, d1s + a_{2p-2})   (== gathered fstate, bit-exact)
        float inj = __int_as_float(pv.z) + aEnter;   // ready before g1 returns
        float fp = (pv.x < 0) ? BIGF : fminf(__int_as_float(g1), inj);
        // pair chains
        float d0 = __int_as_float(pv.y);
        float d1 = __int_as_float(cv.y);
        float v0 = d0 + (fp - LMBDA);        // lanes<32: A0 ; lanes>=32: pre_t0
        float A1 = d1 + (v0 - LMBDA);
        float B0 = d0 + alpha;               // uses a_{2p-1}
        float B1 = d1 + (B0 - LMBDA);
        float mab = fminf(A1, B1);
        float x = (lane < 32) ? mab : v0;
        float red = dpp_min32(x);
        float Pp0 = rdlane(red, 63);         // min pre_t0 over t0 slots
        float a0 = fminf(Pp0, dm0 + alpha);  // a_{2p}
        areg = (((2 * p) & 63) == lane) ? a0 : areg;   // even pos: never flushes
        mabprev = mab;
        redAB = red;                          // lane 31 = P_AB1, consumed next pair
        dmT1prev = dm1;
        alpha = a0;
      }
    }
  }
  // epilogue: a_{T-1}
  float Pab = rdlane(redAB, 31);
  alpha = fminf(Pab, dmT1prev + alpha);
  areg = (lane == 63) ? alpha : areg;
  alphaOut[(T_N - 64) + lane] = areg;
}

// ---------------- pass2: chunked warm-start replay per k (WARM=64 validated; CH=256) --------
#define CH 256
#define WARM 64
__global__ __launch_bounds__(256) void k_pass2(const float* __restrict__ d2,
                                               const float* __restrict__ AOUT,
                                               unsigned* __restrict__ pack) {
  int kb = blockIdx.x & 3;
  int tc = blockIdx.x >> 2;
  int k = kb * 256 + threadIdx.x;
  int ts = tc * CH;
  int start = ts - WARM; if (start < 0) start = 0;
  int end = ts + CH;
  __shared__ float lal[CH + WARM + 1];
  for (int i = threadIdx.x; i < end - start + 1; i += 256) {
    int idx = start - 1 + i;
    lal[i] = (idx < 0) ? 0.0f : AOUT[idx];
  }
  __syncthreads();
  float f = BIGF;
  unsigned s = 0;
#pragma unroll 4
  for (int tau = start; tau < end; ++tau) {
    float a_in = lal[tau - start];
    float d = d2[(size_t)tau * K_N + k];
    float ext = f - LMBDA;
    if (a_in < ext) s = (unsigned)tau;
    f = d + fminf(a_in, ext);
    if (tau >= ts) {
      float a_out = lal[tau - start + 1];
      if (f == a_out) atomicMin(&pack[tau], ((unsigned)k << 13) | s);
    }
  }
}

// ---------------- backtrack: ballot run-skip serial chase + parallel fill (validated r1) ----------------
__global__ __launch_bounds__(256) void k_backtrack(const unsigned* __restrict__ pack,
                                                   unsigned* __restrict__ unitsWs,
                                                   float* __restrict__ outUnits) {
  __shared__ unsigned lp[T_N];
  __shared__ unsigned long long msk[T_N / 64];
  int tid = threadIdx.x;
  for (int i = tid * 4; i < T_N; i += 1024) {
    *(uint4*)&lp[i] = *(const uint4*)&pack[i];
  }
  __syncthreads();
  if (tid < 64) {
    int lane = tid;
    int cur = T_N;
    for (int B = T_N - 64; B >= 0; B -= 64) {
      unsigned long long marks = 0ull;
      if (cur > B) {
        unsigned pk = lp[B + lane];
        int bv = (int)(pk & 8191u);
        unsigned long long run = __ballot(bv == B + lane);
        while (cur > B) {
          int L = cur - 1 - B;
          unsigned long long below = (L == 63) ? ~0ull : ((1ull << (L + 1)) - 1ull);
          unsigned long long nz = (~run) & below;
          if (nz == 0ull) { marks |= below; cur = B; break; }
          int j = 63 - __builtin_clzll(nz);
          marks |= below & ~((1ull << j) - 1ull);
          int nb = __builtin_amdgcn_readlane(bv, j);
          cur = nb;
          if (cur > B + j) cur = B + j;
        }
      }
      if (lane == 0) msk[B >> 6] = marks;
    }
  }
  __syncthreads();
  for (int p = tid; p < T_N; p += 256) {
    int w = p >> 6;
    unsigned long long m = msk[w] & (~0ull << (p & 63));
    while (m == 0ull) { ++w; m = msk[w]; }
    int idx = (w << 6) + (int)__builtin_ctzll(m);
    unsigned g = (lp[idx] >> 13) & 1023u;
    unitsWs[p] = g;
    outUnits[p] = (float)g;
  }
}

// ---------------- gather: quantized[t] = codebook[units[t]] ----------------
__global__ __launch_bounds__(256) void k_gather(const float* __restrict__ C,
                                                const unsigned* __restrict__ unitsWs,
                                                float* __restrict__ out) {
  int t = blockIdx.x;
  unsigned u = unitsWs[t] & 1023u;
  const float4* src = (const float4*)(C + (size_t)u * D_N);
  float4* dst = (float4*)(out + (size_t)t * D_N);
  dst[threadIdx.x] = src[threadIdx.x];
}

extern "C" void kernel_launch(void* const* d_in, const int* in_sizes, int n_in,
                              void* d_out, int out_size, void* d_ws, size_t ws_size,
                              hipStream_t stream) {
  const float* F = (const float*)d_in[0];
  const float* C = (const float*)d_in[1];
  float* out = (float*)d_out;
  float* d2 = out;                                  // reuse quantized region as d2 scratch
  float* outUnits = out + (size_t)T_N * D_N;
  char* ws = (char*)d_ws;
  float* alphaOut = (float*)(ws);                    // 32 KB
  unsigned* pack = (unsigned*)(ws + (32 << 10));     // 32 KB
  unsigned* unitsWs = (unsigned*)(ws + (64 << 10));  // 32 KB
  float* sf2 = (float*)(ws + (96 << 10));            // 32 KB
  float* sc2 = (float*)(ws + (128 << 10));           // 4 KB
  float* dminArr = (float*)(ws + (160 << 10));       // 32 KB
  int2* cand = (int2*)(ws + (1 << 20));              // 2 MB (8192 x 32 x 8B)
  int4* pairbuf = (int4*)(ws + (3 << 20));           // 4 MB (4096 x 64 x 16B)

  k_norms<<<(T_N + K_N) / 4, 256, 0, stream>>>(F, C, sf2, sc2);
  hipMemsetAsync(pack, 0xFF, T_N * sizeof(unsigned), stream);
  hipMemsetAsync(cand, 0xFF, (size_t)T_N * CMAX * sizeof(int2), stream);
  k_gemm<<<(T_N / 64) * (K_N / 128), 256, 0, stream>>>(F, C, sf2, sc2, d2);
  k_cand<<<T_N / 4, 256, 0, stream>>>(d2, cand, dminArr);
  k_prev2<<<(T_N / 2) / 4, 256, 0, stream>>>(cand, pairbuf);
  k_pass1<<<1, 64, 0, stream>>>(pairbuf, cand, dminArr, alphaOut);
  k_pass2<<<(T_N / CH) * 4, 256, 0, stream>>>(d2, alphaOut, pack);
  k_backtrack<<<1, 256, 0, stream>>>(pack, unitsWs, outUnits);
  k_gather<<<T_N, 256, 0, stream>>>(C, unitsWs, out);
}

// Round 20
// 899.857 us; speedup vs baseline: 2.2812x; 1.0574x over previous
//
#include <hip/hip_runtime.h>
#include <hip/hip_bf16.h>
#include <stdint.h>

#define T_N 8192
#define K_N 1024
#define D_N 1024
#define LMBDA 5.0f
#define BIGF 3.0e38f
#define CMAX 32
#define THR 26.0f      // 2*lambda + 4 bound + >10 ulp slack (r9-validated)
#define QNAN 0x7FC00000

// ---------------- norms: numpy-pairwise-exact sum of squares per row ----------------
__global__ __launch_bounds__(256) void k_norms(const float* __restrict__ F,
                                               const float* __restrict__ C,
                                               float* __restrict__ sf2,
                                               float* __restrict__ sc2) {
#pragma clang fp contract(off)
  int wave = threadIdx.x >> 6;
  int lane = threadIdx.x & 63;
  int row = blockIdx.x * 4 + wave;
  const float* src;
  float* dst;
  if (row < T_N) { src = F + (size_t)row * D_N; dst = sf2 + row; }
  else           { src = C + (size_t)(row - T_N) * D_N; dst = sc2 + (row - T_N); }
  int leaf = lane >> 3, j = lane & 7;
  const float* p = src + leaf * 128 + j;
  float x = p[0];
  float r = x * x;
#pragma unroll
  for (int i = 1; i < 16; ++i) {
    float y = p[8 * i];
    r = r + y * y;
  }
  r = r + __shfl_xor(r, 1, 64);
  r = r + __shfl_xor(r, 2, 64);
  r = r + __shfl_xor(r, 4, 64);
  r = r + __shfl_xor(r, 8, 64);
  r = r + __shfl_xor(r, 16, 64);
  r = r + __shfl_xor(r, 32, 64);
  if (lane == 0) *dst = r;
}

// ---------------- d2 GEMM: OpenBLAS-faithful f32, 64x128 tile / 4x8 microtile ----------------
// k-columns per thread: [tx*4, tx*4+4) U [64+tx*4, 64+tx*4+4)  -> LDS reads are 2-way
// (free) instead of 4-way conflicted. Per-output numerics IDENTICAL to r4-validated:
// strictly d-ascending fmaf chain, snapshots after d=383 / d=767, final ((p0+p1)+p2).
__global__ __launch_bounds__(256) void k_gemm(const float* __restrict__ F,
                                              const float* __restrict__ C,
                                              const float* __restrict__ sf2,
                                              const float* __restrict__ sc2,
                                              float* __restrict__ d2) {
  __shared__ float As[32][68];    // [d][t]
  __shared__ float Bs[32][132];   // [d][k]
  int t0 = (int)(blockIdx.x >> 3) * 64;
  int k0 = (int)(blockIdx.x & 7) * 128;
  int tid = threadIdx.x;
  int tx = tid & 15, ty = tid >> 4;     // t: ty*4 ; k: tx*4 and 64+tx*4
  float dot[4][8], acc[4][8];
#pragma unroll
  for (int i = 0; i < 4; ++i)
#pragma unroll
    for (int j = 0; j < 8; ++j) { dot[i][j] = 0.0f; acc[i][j] = 0.0f; }
  int ra = tid & 63, ca = (tid >> 6) * 8;     // A: row ra, d-cols ca..ca+7
  int rb = tid & 127, cb = (tid >> 7) * 16;   // B: row rb, d-cols cb..cb+15
  for (int d0 = 0; d0 < D_N; d0 += 32) {
    __syncthreads();
    {
      const float* fa = &F[(size_t)(t0 + ra) * D_N + d0 + ca];
      float4 a0 = *(const float4*)fa;
      float4 a1 = *(const float4*)(fa + 4);
      As[ca + 0][ra] = a0.x; As[ca + 1][ra] = a0.y; As[ca + 2][ra] = a0.z; As[ca + 3][ra] = a0.w;
      As[ca + 4][ra] = a1.x; As[ca + 5][ra] = a1.y; As[ca + 6][ra] = a1.z; As[ca + 7][ra] = a1.w;
      const float* fb = &C[(size_t)(k0 + rb) * D_N + d0 + cb];
      float4 b0 = *(const float4*)fb;
      float4 b1 = *(const float4*)(fb + 4);
      float4 b2 = *(const float4*)(fb + 8);
      float4 b3 = *(const float4*)(fb + 12);
      Bs[cb + 0][rb] = b0.x; Bs[cb + 1][rb] = b0.y; Bs[cb + 2][rb] = b0.z; Bs[cb + 3][rb] = b0.w;
      Bs[cb + 4][rb] = b1.x; Bs[cb + 5][rb] = b1.y; Bs[cb + 6][rb] = b1.z; Bs[cb + 7][rb] = b1.w;
      Bs[cb + 8][rb] = b2.x; Bs[cb + 9][rb] = b2.y; Bs[cb + 10][rb] = b2.z; Bs[cb + 11][rb] = b2.w;
      Bs[cb + 12][rb] = b3.x; Bs[cb + 13][rb] = b3.y; Bs[cb + 14][rb] = b3.z; Bs[cb + 15][rb] = b3.w;
    }
    __syncthreads();
#pragma unroll
    for (int d = 0; d < 32; ++d) {
      float4 a = *(const float4*)&As[d][ty * 4];
      float4 b0 = *(const float4*)&Bs[d][tx * 4];          // banks tx*4: 2-way = free
      float4 b1 = *(const float4*)&Bs[d][64 + tx * 4];
      float av[4] = {a.x, a.y, a.z, a.w};
      float bv[8] = {b0.x, b0.y, b0.z, b0.w, b1.x, b1.y, b1.z, b1.w};
#pragma unroll
      for (int i = 0; i < 4; ++i)
#pragma unroll
        for (int j = 0; j < 8; ++j)
          acc[i][j] = fmaf(av[i], bv[j], acc[i][j]);
    }
    if (d0 == 352) {      // end of panel [0,384): dot = p0, restart chain
#pragma unroll
      for (int i = 0; i < 4; ++i)
#pragma unroll
        for (int j = 0; j < 8; ++j) { dot[i][j] = acc[i][j]; acc[i][j] = 0.0f; }
    }
    if (d0 == 736) {      // end of panel [384,768): dot = p0 + p1 (rounded add)
#pragma unroll
      for (int i = 0; i < 4; ++i)
#pragma unroll
        for (int j = 0; j < 8; ++j) { dot[i][j] = dot[i][j] + acc[i][j]; acc[i][j] = 0.0f; }
    }
  }
  {
#pragma clang fp contract(off)
#pragma unroll
    for (int i = 0; i < 4; ++i) {
      int t = t0 + ty * 4 + i;
      float sa = sf2[t];
      float o[8];
#pragma unroll
      for (int j = 0; j < 4; ++j) {
        float dsum = dot[i][j] + acc[i][j];
        float two = 2.0f * dsum;
        o[j] = (sa - two) + sc2[k0 + tx * 4 + j];
      }
#pragma unroll
      for (int j = 4; j < 8; ++j) {
        float dsum = dot[i][j] + acc[i][j];
        float two = 2.0f * dsum;
        o[j] = (sa - two) + sc2[k0 + 64 + tx * 4 + (j - 4)];
      }
      float4 o0; o0.x = o[0]; o0.y = o[1]; o0.z = o[2]; o0.w = o[3];
      float4 o1; o1.x = o[4]; o1.y = o[5]; o1.z = o[6]; o1.w = o[7];
      float* dp = &d2[(size_t)t * K_N + k0 + tx * 4];
      *(float4*)dp = o0;
      *(float4*)(dp + 64) = o1;
    }
  }
}

// ---------------- cand: per row, candidate list {k: d <= dmin+THR} + row dmin ----------------
__global__ __launch_bounds__(256) void k_cand(const float* __restrict__ d2,
                                              int2* __restrict__ cand,
                                              float* __restrict__ dminOut) {
  int wave = threadIdx.x >> 6;
  int lane = threadIdx.x & 63;
  int row = blockIdx.x * 4 + wave;
  const float4* p = (const float4*)(d2 + (size_t)row * K_N + lane * 16);
  float4 v0 = p[0], v1 = p[1], v2 = p[2], v3 = p[3];
  float m = fminf(fminf(fminf(v0.x, v0.y), fminf(v0.z, v0.w)),
                  fminf(fminf(v1.x, v1.y), fminf(v1.z, v1.w)));
  float n = fminf(fminf(fminf(v2.x, v2.y), fminf(v2.z, v2.w)),
                  fminf(fminf(v3.x, v3.y), fminf(v3.z, v3.w)));
  m = fminf(m, n);
  m = fminf(m, __shfl_xor(m, 1, 64));
  m = fminf(m, __shfl_xor(m, 2, 64));
  m = fminf(m, __shfl_xor(m, 4, 64));
  m = fminf(m, __shfl_xor(m, 8, 64));
  m = fminf(m, __shfl_xor(m, 16, 64));
  m = fminf(m, __shfl_xor(m, 32, 64));
  if (lane == 0) dminOut[row] = m;
  float thr = m + THR;
  unsigned flags = 0;
#define TESTC(J, VAL) if ((VAL) <= thr) flags |= (1u << (J));
  TESTC(0, v0.x) TESTC(1, v0.y) TESTC(2, v0.z) TESTC(3, v0.w)
  TESTC(4, v1.x) TESTC(5, v1.y) TESTC(6, v1.z) TESTC(7, v1.w)
  TESTC(8, v2.x) TESTC(9, v2.y) TESTC(10, v2.z) TESTC(11, v2.w)
  TESTC(12, v3.x) TESTC(13, v3.y) TESTC(14, v3.z) TESTC(15, v3.w)
#undef TESTC
  int c = __popc(flags);
  int pre = c;
#pragma unroll
  for (int off = 1; off <= 32; off <<= 1) {
    int t = __shfl_up(pre, off, 64);
    if (lane >= off) pre += t;
  }
  int idx = pre - c;
  int2* rowp = cand + (size_t)row * CMAX;
  int kb = lane * 16;
#define EMITC(J, VAL)                                                        \
  if (flags & (1u << (J))) {                                                 \
    if (idx < CMAX) rowp[idx] = make_int2(kb + (J), __float_as_int(VAL));    \
    ++idx;                                                                   \
  }
  EMITC(0, v0.x) EMITC(1, v0.y) EMITC(2, v0.z) EMITC(3, v0.w)
  EMITC(4, v1.x) EMITC(5, v1.y) EMITC(6, v1.z) EMITC(7, v1.w)
  EMITC(8, v2.x) EMITC(9, v2.y) EMITC(10, v2.z) EMITC(11, v2.w)
  EMITC(12, v3.x) EMITC(13, v3.y) EMITC(14, v3.z) EMITC(15, v3.w)
#undef EMITC
}

// ---------------- prev2: per-pair lane data (pp, d0, d1s) for the G=2 pass1 ----------------
__global__ __launch_bounds__(256) void k_prev2(const int2* __restrict__ cand,
                                               int4* __restrict__ pairbuf) {
  __shared__ int km1k[4][32];
  __shared__ int km1d[4][32];
  __shared__ int kt0k[4][32];
  __shared__ int kt0d[4][32];
  int w = threadIdx.x >> 6, lane = threadIdx.x & 63;
  int p = blockIdx.x * 4 + w;
  int t0 = 2 * p, t1 = 2 * p + 1, tm1 = t0 - 1;
  if (lane < 32) {
    int2 c0 = cand[(size_t)t0 * CMAX + lane];
    kt0k[w][lane] = c0.x; kt0d[w][lane] = c0.y;
  } else {
    int j = lane - 32;
    int2 cm = (p > 0) ? cand[(size_t)tm1 * CMAX + j] : make_int2(-2, 0);
    km1k[w][j] = cm.x; km1d[w][j] = cm.y;
  }
  __syncthreads();
  int4 out;
  if (lane < 32) {
    int2 c1 = cand[(size_t)t1 * CMAX + lane];
    int k1 = c1.x;
    int pp2 = -4, d0 = QNAN, d1s = 0;
    bool in0 = false;
#pragma unroll
    for (int i = 0; i < 32; ++i) if (kt0k[w][i] == k1) { d0 = kt0d[w][i]; in0 = true; }
#pragma unroll
    for (int i = 0; i < 32; ++i) if (km1k[w][i] == k1) { pp2 = i * 4; d1s = km1d[w][i]; }
    if (!in0 || k1 < 0) { pp2 = -4; d0 = QNAN; }
    out = make_int4(pp2, d0, d1s, 0);
  } else {
    int i0 = lane - 32;
    int k0 = kt0k[w][i0];
    int d0 = kt0d[w][i0];
    int pp = -4, d1s = 0;
#pragma unroll
    for (int i = 0; i < 32; ++i) if (km1k[w][i] == k0) { pp = i * 4; d1s = km1d[w][i]; }
    if (k0 < 0) pp = -4;   // sentinel slot (d0 already NaN)
    out = make_int4(pp, d0, d1s, 0);
  }
  pairbuf[(size_t)p * 64 + lane] = out;
}

// ---------------- DPP min per 32-lane half (lane 31: lower half; lane 63: upper half) --------
__device__ __forceinline__ float dpp_min32(float x) {
  int t;
  t = __builtin_amdgcn_update_dpp(__float_as_int(x), __float_as_int(x), 0x111, 0xF, 0xF, false);
  x = fminf(x, __int_as_float(t));
  t = __builtin_amdgcn_update_dpp(__float_as_int(x), __float_as_int(x), 0x112, 0xF, 0xF, false);
  x = fminf(x, __int_as_float(t));
  t = __builtin_amdgcn_update_dpp(__float_as_int(x), __float_as_int(x), 0x114, 0xF, 0xF, false);
  x = fminf(x, __int_as_float(t));
  t = __builtin_amdgcn_update_dpp(__float_as_int(x), __float_as_int(x), 0x118, 0xF, 0xF, false);
  x = fminf(x, __int_as_float(t));
  t = __builtin_amdgcn_update_dpp(__float_as_int(x), __float_as_int(x), 0x142, 0xF, 0xF, false); // row_bcast:15
  x = fminf(x, __int_as_float(t));
  return x;
}
__device__ __forceinline__ float rdlane(float x, int l) {
  return __int_as_float(__builtin_amdgcn_readlane(__float_as_int(x), l));
}

// ---------------- pass1: G=2 sparse chain — bpermute payload is alpha-free mab (r16, 559us) --
__global__ __launch_bounds__(64, 1) void k_pass1(const int4* __restrict__ pairbuf,
                                                 const int2* __restrict__ cand,
                                                 const float* __restrict__ dminArr,
                                                 float* __restrict__ alphaOut) {
  const int lane = threadIdx.x;
  const int4* basep = pairbuf + lane;
  const int2* basec = cand + (lane & 31);
  int4 rg[8];
  int2 rgc[8];
#pragma unroll
  for (int u = 0; u < 8; ++u) {
    rg[u] = basep[(size_t)u * 64];
    rgc[u] = basec[(size_t)(2 * u + 1) * CMAX];
  }
  float mabprev = BIGF;     // mab of previous pair (lanes 0-31 meaningful)
  float alpha = 0.0f;       // entering iter p: a_{2p-2}
  float redAB = 0.0f;       // pending lane-31 reduce (P_AB1 of previous pair)
  float dmT1prev = 0.0f;    // dmin_{2p-1}
  float areg = 0.0f;
  float dmv_next = dminArr[lane];
  const int NP = T_N / 2;
  for (int pb32 = 0; pb32 < NP; pb32 += 32) {
    float dmv = dmv_next;
    int nb = pb32 + 32; if (nb >= NP) nb = 0;
    dmv_next = dminArr[2 * nb + lane];
    for (int pb8 = 0; pb8 < 32; pb8 += 8) {
#pragma unroll
      for (int u = 0; u < 8; ++u) {
        int p = pb32 + pb8 + u;
        int4 pv = rg[u];
        int2 cv = rgc[u];
        float aEnter = alpha;                        // a_{2p-2}
        // the pair's single bpermute: payload mab (alpha-free, ready since last iter)
        int g1 = __builtin_amdgcn_ds_bpermute(pv.x, __float_as_int(mabprev));
        // prefetch pair p+8
        int pn = p + 8; if (pn > NP - 1) pn = NP - 1;
        rg[u] = basep[(size_t)pn * 64];
        rgc[u] = basec[(size_t)(2 * pn + 1) * CMAX];
        // finalize a_{2p-1} (off the gather chain)
        float Pab = rdlane(redAB, 31);
        alpha = fminf(Pab, dmT1prev + aEnter);       // a_{2p-1}
        int posA = 2 * p - 1;
        if (posA >= 0) {
          areg = ((posA & 63) == lane) ? alpha : areg;
          if ((posA & 63) == 63) alphaOut[(posA & ~63) + lane] = areg;
        }
        int r0 = 2 * (pb8 + u);
        float dm0 = rdlane(dmv, r0);
        float dm1 = rdlane(dmv, r0 + 1);
        // fp = min(mab_g, d1s + a_{2p-2})   (== gathered fstate, bit-exact)
        float inj = __int_as_float(pv.z) + aEnter;   // ready before g1 returns
        float fp = (pv.x < 0) ? BIGF : fminf(__int_as_float(g1), inj);
        // pair chains
        float d0 = __int_as_float(pv.y);
        float d1 = __int_as_float(cv.y);
        float v0 = d0 + (fp - LMBDA);        // lanes<32: A0 ; lanes>=32: pre_t0
        float A1 = d1 + (v0 - LMBDA);
        float B0 = d0 + alpha;               // uses a_{2p-1}
        float B1 = d1 + (B0 - LMBDA);
        float mab = fminf(A1, B1);
        float x = (lane < 32) ? mab : v0;
        float red = dpp_min32(x);
        float Pp0 = rdlane(red, 63);         // min pre_t0 over t0 slots
        float a0 = fminf(Pp0, dm0 + alpha);  // a_{2p}
        areg = (((2 * p) & 63) == lane) ? a0 : areg;   // even pos: never flushes
        mabprev = mab;
        redAB = red;                          // lane 31 = P_AB1, consumed next pair
        dmT1prev = dm1;
        alpha = a0;
      }
    }
  }
  // epilogue: a_{T-1}
  float Pab = rdlane(redAB, 31);
  alpha = fminf(Pab, dmT1prev + alpha);
  areg = (lane == 63) ? alpha : areg;
  alphaOut[(T_N - 64) + lane] = areg;
}

// ---------------- pass2: chunked warm-start replay per k (WARM=64 validated; CH=128) --------
#define CH 128
#define WARM 64
__global__ __launch_bounds__(256) void k_pass2(const float* __restrict__ d2,
                                               const float* __restrict__ AOUT,
                                               unsigned* __restrict__ pack) {
  int kb = blockIdx.x & 3;
  int tc = blockIdx.x >> 2;
  int k = kb * 256 + threadIdx.x;
  int ts = tc * CH;
  int start = ts - WARM; if (start < 0) start = 0;
  int end = ts + CH;
  __shared__ float lal[CH + WARM + 1];
  for (int i = threadIdx.x; i < end - start + 1; i += 256) {
    int idx = start - 1 + i;
    lal[i] = (idx < 0) ? 0.0f : AOUT[idx];
  }
  __syncthreads();
  float f = BIGF;
  unsigned s = 0;
#pragma unroll 4
  for (int tau = start; tau < end; ++tau) {
    float a_in = lal[tau - start];
    float d = d2[(size_t)tau * K_N + k];
    float ext = f - LMBDA;
    if (a_in < ext) s = (unsigned)tau;
    f = d + fminf(a_in, ext);
    if (tau >= ts) {
      float a_out = lal[tau - start + 1];
      if (f == a_out) atomicMin(&pack[tau], ((unsigned)k << 13) | s);
    }
  }
}

// ---------------- backtrack: ballot run-skip serial chase + parallel fill (validated r1) ----------------
__global__ __launch_bounds__(256) void k_backtrack(const unsigned* __restrict__ pack,
                                                   unsigned* __restrict__ unitsWs,
                                                   float* __restrict__ outUnits) {
  __shared__ unsigned lp[T_N];
  __shared__ unsigned long long msk[T_N / 64];
  int tid = threadIdx.x;
  for (int i = tid * 4; i < T_N; i += 1024) {
    *(uint4*)&lp[i] = *(const uint4*)&pack[i];
  }
  __syncthreads();
  if (tid < 64) {
    int lane = tid;
    int cur = T_N;
    for (int B = T_N - 64; B >= 0; B -= 64) {
      unsigned long long marks = 0ull;
      if (cur > B) {
        unsigned pk = lp[B + lane];
        int bv = (int)(pk & 8191u);
        unsigned long long run = __ballot(bv == B + lane);
        while (cur > B) {
          int L = cur - 1 - B;
          unsigned long long below = (L == 63) ? ~0ull : ((1ull << (L + 1)) - 1ull);
          unsigned long long nz = (~run) & below;
          if (nz == 0ull) { marks |= below; cur = B; break; }
          int j = 63 - __builtin_clzll(nz);
          marks |= below & ~((1ull << j) - 1ull);
          int nb = __builtin_amdgcn_readlane(bv, j);
          cur = nb;
          if (cur > B + j) cur = B + j;
        }
      }
      if (lane == 0) msk[B >> 6] = marks;
    }
  }
  __syncthreads();
  for (int p = tid; p < T_N; p += 256) {
    int w = p >> 6;
    unsigned long long m = msk[w] & (~0ull << (p & 63));
    while (m == 0ull) { ++w; m = msk[w]; }
    int idx = (w << 6) + (int)__builtin_ctzll(m);
    unsigned g = (lp[idx] >> 13) & 1023u;
    unitsWs[p] = g;
    outUnits[p] = (float)g;
  }
}

// ---------------- gather: quantized[t] = codebook[units[t]] ----------------
__global__ __launch_bounds__(256) void k_gather(const float* __restrict__ C,
                                                const unsigned* __restrict__ unitsWs,
                                                float* __restrict__ out) {
  int t = blockIdx.x;
  unsigned u = unitsWs[t] & 1023u;
  const float4* src = (const float4*)(C + (size_t)u * D_N);
  float4* dst = (float4*)(out + (size_t)t * D_N);
  dst[threadIdx.x] = src[threadIdx.x];
}

extern "C" void kernel_launch(void* const* d_in, const int* in_sizes, int n_in,
                              void* d_out, int out_size, void* d_ws, size_t ws_size,
                              hipStream_t stream) {
  const float* F = (const float*)d_in[0];
  const float* C = (const float*)d_in[1];
  float* out = (float*)d_out;
  float* d2 = out;                                  // reuse quantized region as d2 scratch
  float* outUnits = out + (size_t)T_N * D_N;
  char* ws = (char*)d_ws;
  float* alphaOut = (float*)(ws);                    // 32 KB
  unsigned* pack = (unsigned*)(ws + (32 << 10));     // 32 KB
  unsigned* unitsWs = (unsigned*)(ws + (64 << 10));  // 32 KB
  float* sf2 = (float*)(ws + (96 << 10));            // 32 KB
  float* sc2 = (float*)(ws + (128 << 10));           // 4 KB
  float* dminArr = (float*)(ws + (160 << 10));       // 32 KB
  int2* cand = (int2*)(ws + (1 << 20));              // 2 MB (8192 x 32 x 8B)
  int4* pairbuf = (int4*)(ws + (3 << 20));           // 4 MB (4096 x 64 x 16B)

  k_norms<<<(T_N + K_N) / 4, 256, 0, stream>>>(F, C, sf2, sc2);
  hipMemsetAsync(pack, 0xFF, T_N * sizeof(unsigned), stream);
  hipMemsetAsync(cand, 0xFF, (size_t)T_N * CMAX * sizeof(int2), stream);
  k_gemm<<<(T_N / 64) * (K_N / 128), 256, 0, stream>>>(F, C, sf2, sc2, d2);
  k_cand<<<T_N / 4, 256, 0, stream>>>(d2, cand, dminArr);
  k_prev2<<<(T_N / 2) / 4, 256, 0, stream>>>(cand, pairbuf);
  k_pass1<<<1, 64, 0, stream>>>(pairbuf, cand, dminArr, alphaOut);
  k_pass2<<<(T_N / CH) * 4, 256, 0, stream>>>(d2, alphaOut, pack);
  k_backtrack<<<1, 256, 0, stream>>>(pack, unitsWs, outUnits);
  k_gather<<<T_N, 256, 0, stream>>>(C, unitsWs, out);
}

// Round 21
// 849.909 us; speedup vs baseline: 2.4153x; 1.0588x over previous
//
#include <hip/hip_runtime.h>
#include <hip/hip_bf16.h>
#include <stdint.h>

#define T_N 8192
#define K_N 1024
#define D_N 1024
#define LMBDA 5.0f
#define BIGF 3.0e38f
#define CMAX 16
#define THR 26.0f      // 2*lambda + 4 bound + >10 ulp slack (r9-validated)
#define QNAN 0x7FC00000

// ---------------- norms: numpy-pairwise-exact sum of squares per row ----------------
__global__ __launch_bounds__(256) void k_norms(const float* __restrict__ F,
                                               const float* __restrict__ C,
                                               float* __restrict__ sf2,
                                               float* __restrict__ sc2) {
#pragma clang fp contract(off)
  int wave = threadIdx.x >> 6;
  int lane = threadIdx.x & 63;
  int row = blockIdx.x * 4 + wave;
  const float* src;
  float* dst;
  if (row < T_N) { src = F + (size_t)row * D_N; dst = sf2 + row; }
  else           { src = C + (size_t)(row - T_N) * D_N; dst = sc2 + (row - T_N); }
  int leaf = lane >> 3, j = lane & 7;
  const float* p = src + leaf * 128 + j;
  float x = p[0];
  float r = x * x;
#pragma unroll
  for (int i = 1; i < 16; ++i) {
    float y = p[8 * i];
    r = r + y * y;
  }
  r = r + __shfl_xor(r, 1, 64);
  r = r + __shfl_xor(r, 2, 64);
  r = r + __shfl_xor(r, 4, 64);
  r = r + __shfl_xor(r, 8, 64);
  r = r + __shfl_xor(r, 16, 64);
  r = r + __shfl_xor(r, 32, 64);
  if (lane == 0) *dst = r;
}

// ---------------- d2 GEMM: OpenBLAS-faithful f32, 64x128 tile / 4x8 microtile (r19/r20) -----
__global__ __launch_bounds__(256) void k_gemm(const float* __restrict__ F,
                                              const float* __restrict__ C,
                                              const float* __restrict__ sf2,
                                              const float* __restrict__ sc2,
                                              float* __restrict__ d2) {
  __shared__ float As[32][68];    // [d][t]
  __shared__ float Bs[32][132];   // [d][k]
  int t0 = (int)(blockIdx.x >> 3) * 64;
  int k0 = (int)(blockIdx.x & 7) * 128;
  int tid = threadIdx.x;
  int tx = tid & 15, ty = tid >> 4;
  float dot[4][8], acc[4][8];
#pragma unroll
  for (int i = 0; i < 4; ++i)
#pragma unroll
    for (int j = 0; j < 8; ++j) { dot[i][j] = 0.0f; acc[i][j] = 0.0f; }
  int ra = tid & 63, ca = (tid >> 6) * 8;
  int rb = tid & 127, cb = (tid >> 7) * 16;
  for (int d0 = 0; d0 < D_N; d0 += 32) {
    __syncthreads();
    {
      const float* fa = &F[(size_t)(t0 + ra) * D_N + d0 + ca];
      float4 a0 = *(const float4*)fa;
      float4 a1 = *(const float4*)(fa + 4);
      As[ca + 0][ra] = a0.x; As[ca + 1][ra] = a0.y; As[ca + 2][ra] = a0.z; As[ca + 3][ra] = a0.w;
      As[ca + 4][ra] = a1.x; As[ca + 5][ra] = a1.y; As[ca + 6][ra] = a1.z; As[ca + 7][ra] = a1.w;
      const float* fb = &C[(size_t)(k0 + rb) * D_N + d0 + cb];
      float4 b0 = *(const float4*)fb;
      float4 b1 = *(const float4*)(fb + 4);
      float4 b2 = *(const float4*)(fb + 8);
      float4 b3 = *(const float4*)(fb + 12);
      Bs[cb + 0][rb] = b0.x; Bs[cb + 1][rb] = b0.y; Bs[cb + 2][rb] = b0.z; Bs[cb + 3][rb] = b0.w;
      Bs[cb + 4][rb] = b1.x; Bs[cb + 5][rb] = b1.y; Bs[cb + 6][rb] = b1.z; Bs[cb + 7][rb] = b1.w;
      Bs[cb + 8][rb] = b2.x; Bs[cb + 9][rb] = b2.y; Bs[cb + 10][rb] = b2.z; Bs[cb + 11][rb] = b2.w;
      Bs[cb + 12][rb] = b3.x; Bs[cb + 13][rb] = b3.y; Bs[cb + 14][rb] = b3.z; Bs[cb + 15][rb] = b3.w;
    }
    __syncthreads();
#pragma unroll
    for (int d = 0; d < 32; ++d) {
      float4 a = *(const float4*)&As[d][ty * 4];
      float4 b0 = *(const float4*)&Bs[d][tx * 4];
      float4 b1 = *(const float4*)&Bs[d][64 + tx * 4];
      float av[4] = {a.x, a.y, a.z, a.w};
      float bv[8] = {b0.x, b0.y, b0.z, b0.w, b1.x, b1.y, b1.z, b1.w};
#pragma unroll
      for (int i = 0; i < 4; ++i)
#pragma unroll
        for (int j = 0; j < 8; ++j)
          acc[i][j] = fmaf(av[i], bv[j], acc[i][j]);
    }
    if (d0 == 352) {
#pragma unroll
      for (int i = 0; i < 4; ++i)
#pragma unroll
        for (int j = 0; j < 8; ++j) { dot[i][j] = acc[i][j]; acc[i][j] = 0.0f; }
    }
    if (d0 == 736) {
#pragma unroll
      for (int i = 0; i < 4; ++i)
#pragma unroll
        for (int j = 0; j < 8; ++j) { dot[i][j] = dot[i][j] + acc[i][j]; acc[i][j] = 0.0f; }
    }
  }
  {
#pragma clang fp contract(off)
#pragma unroll
    for (int i = 0; i < 4; ++i) {
      int t = t0 + ty * 4 + i;
      float sa = sf2[t];
      float o[8];
#pragma unroll
      for (int j = 0; j < 4; ++j) {
        float dsum = dot[i][j] + acc[i][j];
        float two = 2.0f * dsum;
        o[j] = (sa - two) + sc2[k0 + tx * 4 + j];
      }
#pragma unroll
      for (int j = 4; j < 8; ++j) {
        float dsum = dot[i][j] + acc[i][j];
        float two = 2.0f * dsum;
        o[j] = (sa - two) + sc2[k0 + 64 + tx * 4 + (j - 4)];
      }
      float4 o0; o0.x = o[0]; o0.y = o[1]; o0.z = o[2]; o0.w = o[3];
      float4 o1; o1.x = o[4]; o1.y = o[5]; o1.z = o[6]; o1.w = o[7];
      float* dp = &d2[(size_t)t * K_N + k0 + tx * 4];
      *(float4*)dp = o0;
      *(float4*)(dp + 64) = o1;
    }
  }
}

// ---------------- cand: per row, candidate list {k: d <= dmin+THR} + row dmin (CMAX=16) -----
__global__ __launch_bounds__(256) void k_cand(const float* __restrict__ d2,
                                              int2* __restrict__ cand,
                                              float* __restrict__ dminOut) {
  int wave = threadIdx.x >> 6;
  int lane = threadIdx.x & 63;
  int row = blockIdx.x * 4 + wave;
  const float4* p = (const float4*)(d2 + (size_t)row * K_N + lane * 16);
  float4 v0 = p[0], v1 = p[1], v2 = p[2], v3 = p[3];
  float m = fminf(fminf(fminf(v0.x, v0.y), fminf(v0.z, v0.w)),
                  fminf(fminf(v1.x, v1.y), fminf(v1.z, v1.w)));
  float n = fminf(fminf(fminf(v2.x, v2.y), fminf(v2.z, v2.w)),
                  fminf(fminf(v3.x, v3.y), fminf(v3.z, v3.w)));
  m = fminf(m, n);
  m = fminf(m, __shfl_xor(m, 1, 64));
  m = fminf(m, __shfl_xor(m, 2, 64));
  m = fminf(m, __shfl_xor(m, 4, 64));
  m = fminf(m, __shfl_xor(m, 8, 64));
  m = fminf(m, __shfl_xor(m, 16, 64));
  m = fminf(m, __shfl_xor(m, 32, 64));
  if (lane == 0) dminOut[row] = m;
  float thr = m + THR;
  unsigned flags = 0;
#define TESTC(J, VAL) if ((VAL) <= thr) flags |= (1u << (J));
  TESTC(0, v0.x) TESTC(1, v0.y) TESTC(2, v0.z) TESTC(3, v0.w)
  TESTC(4, v1.x) TESTC(5, v1.y) TESTC(6, v1.z) TESTC(7, v1.w)
  TESTC(8, v2.x) TESTC(9, v2.y) TESTC(10, v2.z) TESTC(11, v2.w)
  TESTC(12, v3.x) TESTC(13, v3.y) TESTC(14, v3.z) TESTC(15, v3.w)
#undef TESTC
  int c = __popc(flags);
  int pre = c;
#pragma unroll
  for (int off = 1; off <= 32; off <<= 1) {
    int t = __shfl_up(pre, off, 64);
    if (lane >= off) pre += t;
  }
  int idx = pre - c;
  int2* rowp = cand + (size_t)row * CMAX;
  int kb = lane * 16;
#define EMITC(J, VAL)                                                        \
  if (flags & (1u << (J))) {                                                 \
    if (idx < CMAX) rowp[idx] = make_int2(kb + (J), __float_as_int(VAL));    \
    ++idx;                                                                   \
  }
  EMITC(0, v0.x) EMITC(1, v0.y) EMITC(2, v0.z) EMITC(3, v0.w)
  EMITC(4, v1.x) EMITC(5, v1.y) EMITC(6, v1.z) EMITC(7, v1.w)
  EMITC(8, v2.x) EMITC(9, v2.y) EMITC(10, v2.z) EMITC(11, v2.w)
  EMITC(12, v3.x) EMITC(13, v3.y) EMITC(14, v3.z) EMITC(15, v3.w)
#undef EMITC
}

// ---------------- prev4: per-group (4 rows x 16 slots) lane statics ----------------
// Lane L (s=L&15): quadrant q = 3-(L>>4) -> row 4g+q. Statics for its k:
//   pp  = byteaddr of k in S_{4g-1} list (-4 if absent / sentinel)
//   d_own, d0s/d1s/d2s = d of k in rows 4g..4g+2 (self-lookup gives d_own for own row)
//   p3s = d_{4g-1}[k]  (E-injection).  Absent lookups = NaN (validated chain-death).
__global__ __launch_bounds__(256) void k_prev4(const int2* __restrict__ cand,
                                               int4* __restrict__ pb1,
                                               int2* __restrict__ pb2) {
  __shared__ int2 rows[4][5][16];   // [wave][4g-1, t0, t1, t2, t3][slot]
  int w = threadIdx.x >> 6, lane = threadIdx.x & 63;
  int g = blockIdx.x * 4 + w;
  int base = 4 * g - 1;
  for (int i = lane; i < 80; i += 64) {
    int rr = i >> 4, ss = i & 15;
    int trow = base + rr;
    rows[w][rr][ss] = (trow >= 0) ? cand[(size_t)trow * CMAX + ss] : make_int2(-2, 0);
  }
  __syncthreads();
  int q = 3 - (lane >> 4);
  int s = lane & 15;
  int2 me = rows[w][1 + q][s];
  int k = me.x;
  int pp = -4, p3s = QNAN;
  int d0s = QNAN, d1s = QNAN, d2s = QNAN;
#pragma unroll
  for (int i = 0; i < 16; ++i) {
    if (rows[w][0][i].x == k) { pp = i * 4; p3s = rows[w][0][i].y; }
    if (rows[w][1][i].x == k) d0s = rows[w][1][i].y;
    if (rows[w][2][i].x == k) d1s = rows[w][2][i].y;
    if (rows[w][3][i].x == k) d2s = rows[w][3][i].y;
  }
  if (k < 0) pp = -4;
  pb1[(size_t)g * 64 + lane] = make_int4(pp, me.y, d0s, d1s);
  pb2[(size_t)g * 64 + lane] = make_int2(d2s, p3s);
}

// ---------------- DPP min within each 16-lane row (result at lanes 15/31/47/63) -------------
__device__ __forceinline__ float dpp_min16(float x) {
  int t;
  t = __builtin_amdgcn_update_dpp(__float_as_int(x), __float_as_int(x), 0x111, 0xF, 0xF, false);
  x = fminf(x, __int_as_float(t));
  t = __builtin_amdgcn_update_dpp(__float_as_int(x), __float_as_int(x), 0x112, 0xF, 0xF, false);
  x = fminf(x, __int_as_float(t));
  t = __builtin_amdgcn_update_dpp(__float_as_int(x), __float_as_int(x), 0x114, 0xF, 0xF, false);
  x = fminf(x, __int_as_float(t));
  t = __builtin_amdgcn_update_dpp(__float_as_int(x), __float_as_int(x), 0x118, 0xF, 0xF, false);
  x = fminf(x, __int_as_float(t));
  return x;
}
__device__ __forceinline__ float rdlane(float x, int l) {
  return __int_as_float(__builtin_amdgcn_readlane(__float_as_int(x), l));
}

// ---------------- pass1: G=4 sparse chain — ONE bpermute per FOUR rows ----------------
// fp = f_{4g-1} = min(gather(x3_red_prev), p3s + a_{4g-2})      [E-injection, r16]
// A-walk (boundary) / B-walk (start t0, from ain=a_{4g-1}) depth 0..3; per-quadrant select.
// a_t0 = Q0(min(A0,B0));  a_t1 = min(Q1(..), dmin1+a_t0)        [dmin trick]
// x2_red = min(A2,B2,C2); x3_red = min(A3,B3,C3,D3)  (C,D from a_t0,a_t1 in-iteration)
// a_t2/a_t3 finalized NEXT iteration from carried red2 (pipelined reduce, r16/r17).
// Payload = x3_red (Q3 lanes). All FP ops bit-identical to the reference recurrence.
__global__ __launch_bounds__(64, 1) void k_pass1(const int4* __restrict__ pb1,
                                                 const int2* __restrict__ pb2,
                                                 const float* __restrict__ dminArr,
                                                 float* __restrict__ alphaOut) {
  const int lane = threadIdx.x;
  const int q = 3 - (lane >> 4);
  const int4* b1p = pb1 + lane;
  const int2* b2p = pb2 + lane;
  int4 r1[4];
  int2 r2[4];
#pragma unroll
  for (int u = 0; u < 4; ++u) {
    r1[u] = b1p[(size_t)u * 64];
    r2[u] = b2p[(size_t)u * 64];
  }
  float pay = 0.0f;         // group 0: pp=-4, value irrelevant
  float red2c = BIGF;       // -> a_{-2..-1} = 0 at iter 0
  float dm2c = 0.0f, dm3c = 0.0f, a1c = 0.0f;
  float areg = 0.0f;
  const int NG = T_N / 4;
  float dmv = dminArr[lane];
  float dmv_next;
  for (int gb = 0; gb < NG; gb += 16) {
    int nb = gb + 16; if (nb >= NG) nb = 0;
    dmv_next = dminArr[nb * 4 + lane];
    for (int g4 = 0; g4 < 16; g4 += 4) {
#pragma unroll
      for (int u = 0; u < 4; ++u) {
        int g = gb + g4 + u;
        int4 pa = r1[u];
        int2 pb = r2[u];
        // the group's single gather (payload from previous iteration)
        int g1 = __builtin_amdgcn_ds_bpermute(pa.x, __float_as_int(pay));
        // prefetch group g+4
        int gn = g + 4; if (gn > NG - 1) gn = NG - 1;
        r1[u] = b1p[(size_t)gn * 64];
        r2[u] = b2p[(size_t)gn * 64];
        // prologue: finalize a_{4g-2}, a_{4g-1} from carried red2
        float at2p = fminf(rdlane(red2c, 31), dm2c + a1c);
        float ain = fminf(rdlane(red2c, 15), dm3c + at2p);
        int posB = 4 * g - 1;
        if (posB >= 0) {
          areg = (((posB - 1) & 63) == lane) ? at2p : areg;
          areg = ((posB & 63) == lane) ? ain : areg;
          if ((posB & 63) == 63) alphaOut[(posB & ~63) + lane] = areg;
        }
        int r0 = 4 * (g4 + u);
        float dm0 = rdlane(dmv, r0);
        float dm1 = rdlane(dmv, r0 + 1);
        float dm2 = rdlane(dmv, r0 + 2);
        float dm3 = rdlane(dmv, r0 + 3);
        // fp with deferred E-injection
        float injE = __int_as_float(pb.y) + at2p;      // p3s + a_{4g-2}
        float fp = (pa.x < 0) ? BIGF : fminf(__int_as_float(g1), injE);
        // A/B walks (own-row d substituted automatically via self-lookup)
        float dOwn = __int_as_float(pa.y);
        float d0s = __int_as_float(pa.z);
        float d1s = __int_as_float(pa.w);
        float d2s = __int_as_float(pb.x);
        float A0 = d0s + (fp - LMBDA);
        float A1 = d1s + (A0 - LMBDA);
        float A2 = d2s + (A1 - LMBDA);
        float A3 = dOwn + (A2 - LMBDA);
        float B0 = d0s + ain;
        float B1 = d1s + (B0 - LMBDA);
        float B2 = d2s + (B1 - LMBDA);
        float B3 = dOwn + (B2 - LMBDA);
        float xA = (q == 0) ? A0 : (q == 1) ? A1 : (q == 2) ? A2 : A3;
        float xB = (q == 0) ? B0 : (q == 1) ? B1 : (q == 2) ? B2 : B3;
        float xAB = fminf(xA, xB);
        float red1 = dpp_min16(xAB);
        float a0 = rdlane(red1, 63);                   // a_t0 (A,B complete for t0)
        float a1 = fminf(rdlane(red1, 47), dm1 + a0);  // a_t1 (+C via dmin)
        areg = (((4 * g) & 63) == lane) ? a0 : areg;       // pos % 4 == 0: never flushes
        areg = (((4 * g + 1) & 63) == lane) ? a1 : areg;   // pos % 4 == 1: never flushes
        // C/D folds for rows t2, t3
        float cw1 = d1s + a0;
        float cw2 = d2s + (cw1 - LMBDA);
        float Cin = (q == 2) ? cw1 : cw2;
        float Cterm = dOwn + (Cin - LMBDA);
        float Dterm = dOwn + ((d2s + a1) - LMBDA);
        Dterm = (q == 3) ? Dterm : __int_as_float(QNAN);
        float xr = fminf(fminf(xAB, Cterm), Dterm);
        float red2 = dpp_min16(xr);
        // carries
        pay = xr;                // Q3 lanes hold the t3-slot payload
        red2c = red2;
        dm2c = dm2; dm3c = dm3; a1c = a1;
      }
    }
    dmv = dmv_next;
  }
  // epilogue: a_{8190}, a_{8191}
  float at2 = fminf(rdlane(red2c, 31), dm2c + a1c);
  float at3 = fminf(rdlane(red2c, 15), dm3c + at2);
  areg = ((8190 & 63) == lane) ? at2 : areg;
  areg = ((8191 & 63) == lane) ? at3 : areg;
  alphaOut[(T_N - 64) + lane] = areg;
}

// ---------------- pass2: chunked warm-start replay per k (WARM=64 validated; CH=128) --------
#define CH 128
#define WARM 64
__global__ __launch_bounds__(256) void k_pass2(const float* __restrict__ d2,
                                               const float* __restrict__ AOUT,
                                               unsigned* __restrict__ pack) {
  int kb = blockIdx.x & 3;
  int tc = blockIdx.x >> 2;
  int k = kb * 256 + threadIdx.x;
  int ts = tc * CH;
  int start = ts - WARM; if (start < 0) start = 0;
  int end = ts + CH;
  __shared__ float lal[CH + WARM + 1];
  for (int i = threadIdx.x; i < end - start + 1; i += 256) {
    int idx = start - 1 + i;
    lal[i] = (idx < 0) ? 0.0f : AOUT[idx];
  }
  __syncthreads();
  float f = BIGF;
  unsigned s = 0;
#pragma unroll 4
  for (int tau = start; tau < end; ++tau) {
    float a_in = lal[tau - start];
    float d = d2[(size_t)tau * K_N + k];
    float ext = f - LMBDA;
    if (a_in < ext) s = (unsigned)tau;
    f = d + fminf(a_in, ext);
    if (tau >= ts) {
      float a_out = lal[tau - start + 1];
      if (f == a_out) atomicMin(&pack[tau], ((unsigned)k << 13) | s);
    }
  }
}

// ---------------- backtrack: ballot run-skip serial chase + parallel fill (validated r1) ----------------
__global__ __launch_bounds__(256) void k_backtrack(const unsigned* __restrict__ pack,
                                                   unsigned* __restrict__ unitsWs,
                                                   float* __restrict__ outUnits) {
  __shared__ unsigned lp[T_N];
  __shared__ unsigned long long msk[T_N / 64];
  int tid = threadIdx.x;
  for (int i = tid * 4; i < T_N; i += 1024) {
    *(uint4*)&lp[i] = *(const uint4*)&pack[i];
  }
  __syncthreads();
  if (tid < 64) {
    int lane = tid;
    int cur = T_N;
    for (int B = T_N - 64; B >= 0; B -= 64) {
      unsigned long long marks = 0ull;
      if (cur > B) {
        unsigned pk = lp[B + lane];
        int bv = (int)(pk & 8191u);
        unsigned long long run = __ballot(bv == B + lane);
        while (cur > B) {
          int L = cur - 1 - B;
          unsigned long long below = (L == 63) ? ~0ull : ((1ull << (L + 1)) - 1ull);
          unsigned long long nz = (~run) & below;
          if (nz == 0ull) { marks |= below; cur = B; break; }
          int j = 63 - __builtin_clzll(nz);
          marks |= below & ~((1ull << j) - 1ull);
          int nb = __builtin_amdgcn_readlane(bv, j);
          cur = nb;
          if (cur > B + j) cur = B + j;
        }
      }
      if (lane == 0) msk[B >> 6] = marks;
    }
  }
  __syncthreads();
  for (int p = tid; p < T_N; p += 256) {
    int w = p >> 6;
    unsigned long long m = msk[w] & (~0ull << (p & 63));
    while (m == 0ull) { ++w; m = msk[w]; }
    int idx = (w << 6) + (int)__builtin_ctzll(m);
    unsigned g = (lp[idx] >> 13) & 1023u;
    unitsWs[p] = g;
    outUnits[p] = (float)g;
  }
}

// ---------------- gather: quantized[t] = codebook[units[t]] ----------------
__global__ __launch_bounds__(256) void k_gather(const float* __restrict__ C,
                                                const unsigned* __restrict__ unitsWs,
                                                float* __restrict__ out) {
  int t = blockIdx.x;
  unsigned u = unitsWs[t] & 1023u;
  const float4* src = (const float4*)(C + (size_t)u * D_N);
  float4* dst = (float4*)(out + (size_t)t * D_N);
  dst[threadIdx.x] = src[threadIdx.x];
}

extern "C" void kernel_launch(void* const* d_in, const int* in_sizes, int n_in,
                              void* d_out, int out_size, void* d_ws, size_t ws_size,
                              hipStream_t stream) {
  const float* F = (const float*)d_in[0];
  const float* C = (const float*)d_in[1];
  float* out = (float*)d_out;
  float* d2 = out;                                  // reuse quantized region as d2 scratch
  float* outUnits = out + (size_t)T_N * D_N;
  char* ws = (char*)d_ws;
  float* alphaOut = (float*)(ws);                    // 32 KB
  unsigned* pack = (unsigned*)(ws + (32 << 10));     // 32 KB
  unsigned* unitsWs = (unsigned*)(ws + (64 << 10));  // 32 KB
  float* sf2 = (float*)(ws + (96 << 10));            // 32 KB
  float* sc2 = (float*)(ws + (128 << 10));           // 4 KB
  float* dminArr = (float*)(ws + (160 << 10));       // 32 KB
  int2* cand = (int2*)(ws + (1 << 20));              // 1 MB (8192 x 16 x 8B)
  int4* pb1 = (int4*)(ws + (3 << 20));               // 2 MB (2048 x 64 x 16B)
  int2* pb2 = (int2*)(ws + (5 << 20));               // 1 MB (2048 x 64 x 8B)

  k_norms<<<(T_N + K_N) / 4, 256, 0, stream>>>(F, C, sf2, sc2);
  hipMemsetAsync(pack, 0xFF, T_N * sizeof(unsigned), stream);
  hipMemsetAsync(cand, 0xFF, (size_t)T_N * CMAX * sizeof(int2), stream);
  k_gemm<<<(T_N / 64) * (K_N / 128), 256, 0, stream>>>(F, C, sf2, sc2, d2);
  k_cand<<<T_N / 4, 256, 0, stream>>>(d2, cand, dminArr);
  k_prev4<<<(T_N / 4) / 4, 256, 0, stream>>>(cand, pb1, pb2);
  k_pass1<<<1, 64, 0, stream>>>(pb1, pb2, dminArr, alphaOut);
  k_pass2<<<(T_N / CH) * 4, 256, 0, stream>>>(d2, alphaOut, pack);
  k_backtrack<<<1, 256, 0, stream>>>(pack, unitsWs, outUnits);
  k_gather<<<T_N, 256, 0, stream>>>(C, unitsWs, out);
}